// Round 12
// baseline (127.679 us; speedup 1.0000x reference)
//
#include <hip/hip_runtime.h>
#include <hip/hip_bf16.h>

// ---------------------------------------------------------------------------
// Sliding-window attention (B=4,S=2048,D=1024,H=16,HD=64,W=256) on gfx950.
// Pipeline: cvt(all + RoPE-table transpose) -> GEMM(QKV, 256x192 8-phase,
//           FUSED epilogue: RoPE'd+prescaled Q, K TOKEN-MAJOR [8192][1024]
//           with FRAGMENT-INNER store order (write-combining friendly),
//           V to VT via in-LDS transpose) -> flash window attn (K+V LDS) ->
//           GEMM(O-proj, 256x128 3-buffer).
// ---------------------------------------------------------------------------

typedef __bf16 bf16_t;
typedef __attribute__((ext_vector_type(8))) __bf16 bf16x8;
typedef __attribute__((ext_vector_type(4))) __bf16 bf16x4;
typedef __attribute__((ext_vector_type(4))) float f32x4;

#define MFMA16(a, b, c) __builtin_amdgcn_mfma_f32_16x16x32_bf16((a), (b), (c), 0, 0, 0)

// async global->LDS, 16 bytes per lane. LDS dest is wave-uniform base + lane*16.
__device__ __forceinline__ void async16(const void* g, void* l) {
    __builtin_amdgcn_global_load_lds(
        (const __attribute__((address_space(1))) unsigned int*)g,
        (__attribute__((address_space(3))) unsigned int*)l, 16, 0, 0);
}

#define BAR() do { asm volatile("" ::: "memory"); __builtin_amdgcn_s_barrier(); \
                   asm volatile("" ::: "memory"); } while (0)
#define VMC(N) asm volatile("s_waitcnt vmcnt(" #N ")" ::: "memory")
#define LGKM0() asm volatile("s_waitcnt lgkmcnt(0)" ::: "memory")

// ---------------------------------------------------------------------------
// Fused f32 -> bf16 convert for all 5 tensors + RoPE table transpose.
// ---------------------------------------------------------------------------
__global__ __launch_bounds__(256) void cvt_all(const float* __restrict__ x,
                                               const float* __restrict__ wq,
                                               const float* __restrict__ wk,
                                               const float* __restrict__ wv,
                                               const float* __restrict__ wo,
                                               const float* __restrict__ fcos,
                                               const float* __restrict__ fsin,
                                               bf16_t* __restrict__ xbf,
                                               bf16_t* __restrict__ wqkv,
                                               bf16_t* __restrict__ wobf,
                                               float* __restrict__ fcosT,
                                               float* __restrict__ fsinT) {
    const int blk = blockIdx.x;
    if (blk >= 6144) {
        const int p = blk - 6144;
        for (int s = threadIdx.x; s < 2048; s += 256) {
            fcosT[p * 2048 + s] = fcos[s * 32 + p];
            fsinT[p * 2048 + s] = fsin[s * 32 + p];
        }
        return;
    }
    const float* s;
    bf16_t* d;
    int base;
    if (blk < 4096)      { s = x;  d = xbf;            base = blk; }
    else if (blk < 4608) { s = wq; d = wqkv;           base = blk - 4096; }
    else if (blk < 5120) { s = wk; d = wqkv + 1048576; base = blk - 4608; }
    else if (blk < 5632) { s = wv; d = wqkv + 2097152; base = blk - 5120; }
    else                 { s = wo; d = wobf;           base = blk - 5632; }
    const int i = (base * 256 + threadIdx.x) * 8;
    float4 a = *(const float4*)(s + i);
    float4 b = *(const float4*)(s + i + 4);
    bf16x8 o;
    o[0] = (bf16_t)a.x; o[1] = (bf16_t)a.y; o[2] = (bf16_t)a.z; o[3] = (bf16_t)a.w;
    o[4] = (bf16_t)b.x; o[5] = (bf16_t)b.y; o[6] = (bf16_t)b.z; o[7] = (bf16_t)b.w;
    *(bf16x8*)(d + i) = o;
}

// ---------------------------------------------------------------------------
// 256x192 8-phase QKV GEMM with FUSED RoPE + layout epilogue.
// Main loop identical to R4/R6 (counted vmcnt, st_16x32 swizzle, 8 waves).
// Epilogue (R12: store-order fix):
//   v: per-wave in-LDS transpose -> VT[bh][64][2048], 64B-coalesced (own pass).
//   q/k: RoPE in-register (+0.125 prescale on q) via transposed tables;
//        TOKEN-MAJOR store [8192][1024], loop nest (ai, nj, j) -- fragment
//        INNER, so the 32B halves of each 64B line are ~4 stores apart
//        (the plain gemm's write-combining-clean pattern; nj-outer was the
//        R7-R11 write amplification).
// ---------------------------------------------------------------------------
__global__ __launch_bounds__(512, 1) __attribute__((amdgpu_waves_per_eu(2)))
void gemm192_qkv(const bf16_t* __restrict__ A, const bf16_t* __restrict__ Bw,
                 const float* __restrict__ fcosT, const float* __restrict__ fsinT,
                 bf16_t* __restrict__ Qo, bf16_t* __restrict__ Ko,
                 bf16_t* __restrict__ VT, int M, int N, int K) {
    __shared__ __attribute__((aligned(16))) bf16_t As[32768];   // 2 x 4u x 8KiB
    __shared__ __attribute__((aligned(16))) bf16_t Bs[24576];   // 2 x 3u x 8KiB
    const int tid = threadIdx.x;
    const int l = tid & 63, w = tid >> 6;
    const int lr = l & 15, lg = l >> 4;
    const int wr = w >> 2, wc = w & 3;          // 2M x 4N

    const int nwg = gridDim.x * gridDim.y;
    const int flat = blockIdx.y * gridDim.x + blockIdx.x;
    const int swz = (flat & 7) * (nwg >> 3) + (flat >> 3);
    const int bx = swz % gridDim.x, by = swz / gridDim.x;
    const long m0 = (long)by * 256, n0 = (long)bx * 192;
    const int NT = K >> 6;
    const int NI = NT >> 1;

    const int p  = w * 1024 + l * 16;
    const int pp = p ^ (((p >> 9) & 1) << 5);
    const int st = pp >> 10;
    const int rSt = (st >> 1) * 16 + ((pp >> 6) & 15);
    const int cSt = (st & 1) * 32 + ((pp >> 4) & 3) * 8;
    const bf16_t* aS = A  + (m0 + rSt) * K + cSt;
    const bf16_t* bS = Bw + (n0 + rSt) * K + cSt;
    const long uK = 64L * K;

    auto stageA = [&](int b, int u, int t) {
        async16(aS + (long)u * uK + (long)t * 64,
                (char*)As + b * 32768 + u * 8192 + w * 1024);
    };
    auto stageB = [&](int b, int u, int t) {
        async16(bS + (long)u * uK + (long)t * 64,
                (char*)Bs + b * 24576 + u * 8192 + w * 1024);
    };

    f32x4 acc[8][3] = {};
    bf16x8 afX[4], afY[4], bfX[3], bfY[3];
    const int swd = (lr & 8) << 2;

    auto loadAF = [&](int b, int mh, int ks, bf16x8 (&dst)[4]) {
#pragma unroll
        for (int mi = 0; mi < 4; ++mi) {
            const int off = (wr * 2 + mh) * 8192 + (mi * 2 + ks) * 1024 +
                            lr * 64 + lg * 16;
            dst[mi] = *(const bf16x8*)((const char*)As + b * 32768 + (off ^ swd));
        }
    };
    auto loadBF = [&](int b, int ks, bf16x8 (&dst)[3]) {
#pragma unroll
        for (int nj = 0; nj < 3; ++nj) {
            const int rg = wc * 48 + nj * 16 + lr;
            const int off = (rg >> 6) * 8192 + (((rg >> 4) & 3) * 2 + ks) * 1024 +
                            lr * 64 + lg * 16;
            dst[nj] = *(const bf16x8*)((const char*)Bs + b * 24576 + (off ^ swd));
        }
    };

#define QMM(MH, AF, BF) do {                                                   \
    __builtin_amdgcn_s_setprio(1);                                             \
    _Pragma("unroll")                                                          \
    for (int mi = 0; mi < 4; ++mi)                                             \
        _Pragma("unroll")                                                      \
        for (int nj = 0; nj < 3; ++nj)                                         \
            acc[(MH)*4+mi][nj] = MFMA16((AF)[mi], (BF)[nj], acc[(MH)*4+mi][nj]); \
    __builtin_amdgcn_s_setprio(0);                                             \
} while (0)

    // ---- prologue ----
    stageA(0, 0, 0); stageA(0, 1, 0); stageA(0, 2, 0); stageA(0, 3, 0);
    stageB(0, 0, 0); stageB(0, 1, 0); stageB(0, 2, 0);
    stageB(1, 0, 1); stageB(1, 1, 1); stageB(1, 2, 1);
    VMC(3);
    BAR();

#pragma unroll 1
    for (int it = 0; it < NI - 1; ++it) {
        const int T = 2 * it;
        loadAF(0, 0, 0, afX); loadBF(0, 0, bfX);
        stageA(1, 0, T + 1); stageA(1, 1, T + 1);
        BAR(); QMM(0, afX, bfX); BAR();
        loadAF(0, 1, 0, afY);
        stageA(1, 2, T + 1); stageA(1, 3, T + 1);
        BAR(); QMM(1, afY, bfX); BAR();
        loadAF(0, 0, 1, afX); loadBF(0, 1, bfY);
        BAR(); QMM(0, afX, bfY); BAR();
        loadAF(0, 1, 1, afY);
        stageB(0, 0, T + 2);
        BAR(); QMM(1, afY, bfY); VMC(1); BAR();
        loadAF(1, 0, 0, afX); loadBF(1, 0, bfX);
        stageB(0, 1, T + 2); stageB(0, 2, T + 2);
        BAR(); QMM(0, afX, bfX); BAR();
        loadAF(1, 1, 0, afY);
        stageA(0, 0, T + 2); stageA(0, 1, T + 2);
        BAR(); QMM(1, afY, bfX); BAR();
        loadAF(1, 0, 1, afX); loadBF(1, 1, bfY);
        stageA(0, 2, T + 2); stageA(0, 3, T + 2);
        BAR(); QMM(0, afX, bfY); BAR();
        loadAF(1, 1, 1, afY);
        stageB(1, 0, T + 3); stageB(1, 1, T + 3); stageB(1, 2, T + 3);
        BAR(); QMM(1, afY, bfY); VMC(3); BAR();
    }

    // ---- final iteration (tiles NT-2 buf0, NT-1 buf1) ----
    {
        loadAF(0, 0, 0, afX); loadBF(0, 0, bfX);
        stageA(1, 0, NT - 1); stageA(1, 1, NT - 1);
        BAR(); QMM(0, afX, bfX); BAR();
        loadAF(0, 1, 0, afY);
        stageA(1, 2, NT - 1); stageA(1, 3, NT - 1);
        BAR(); QMM(1, afY, bfX); BAR();
        loadAF(0, 0, 1, afX); loadBF(0, 1, bfY);
        BAR(); QMM(0, afX, bfY); BAR();
        loadAF(0, 1, 1, afY);
        BAR(); QMM(1, afY, bfY);
        VMC(0); BAR();                 // <- after this, buf0 of As/Bs is free
        loadAF(1, 0, 0, afX); loadBF(1, 0, bfX);
        QMM(0, afX, bfX);
        loadAF(1, 1, 0, afY);
        QMM(1, afY, bfX);
        loadAF(1, 0, 1, afX); loadBF(1, 1, bfY);
        QMM(0, afX, bfY);
        loadAF(1, 1, 1, afY);
        QMM(1, afY, bfY);
    }
#undef QMM

    // ---- FUSED epilogue ----
    bf16_t* scr = (w < 6) ? (bf16_t*)((char*)As + w * 4608)
                          : (bf16_t*)((char*)Bs + (w - 6) * 4608);
    asm volatile("" ::: "memory");

    // ---- V pass (fragments with cls==2): LDS transpose, 64B stores ----
#pragma unroll
    for (int nj = 0; nj < 3; ++nj) {
        const int cbase = (int)n0 + wc * 48 + nj * 16;
        if ((cbase >> 10) != 2) continue;
#pragma unroll
        for (int ai = 0; ai < 8; ++ai)
#pragma unroll
            for (int j = 0; j < 4; ++j)
                scr[(ai * 16 + lg * 4 + j) * 18 + lr] = (bf16_t)acc[ai][nj][j];
        LGKM0();
        asm volatile("" ::: "memory");
        const int ch = l >> 2;                       // channel 0..15
        const int sub = l & 3;                       // 16B chunk within 64B
        const int d16 = cbase - 2048 + ch;
        const int hh = d16 >> 6, dd = d16 & 63;
        const long T0 = m0 + wr * 128;
        const int bb = (int)(T0 >> 11);
        const int s0 = (int)(T0 & 2047);
        bf16_t* vrow = VT + ((long)((bb * 16 + hh) * 64 + dd) * 2048) + s0;
#pragma unroll
        for (int qq = 0; qq < 4; ++qq) {
            const int tb8 = qq * 32 + sub * 8;       // token base of chunk
            bf16x8 o;
#pragma unroll
            for (int j = 0; j < 8; ++j) {
                const int f = ((j & 3) << 1) | (j >> 2);  // pos j holds key f
                o[j] = scr[(tb8 + f) * 18 + ch];
            }
            *(bf16x8*)(vrow + tb8) = o;
        }
        LGKM0();
        asm volatile("" ::: "memory");
    }

    // ---- Q/K pass: (ai, nj, j) -- fragment-INNER store order ----
    {
        const float sgn = (lr & 1) ? 1.f : -1.f;
#pragma unroll
        for (int ai = 0; ai < 8; ++ai) {
            const long t0 = m0 + wr * 128 + ai * 16 + lg * 4;
            const int s0 = (int)(t0 & 2047);
#pragma unroll
            for (int nj = 0; nj < 3; ++nj) {
                const int cbase = (int)n0 + wc * 48 + nj * 16;
                const int cls = cbase >> 10;         // 0=q,1=k,2=v (uniform)
                if (cls == 2) continue;
                const int c = cbase + lr;
                const int cq = c & 1023;
                const int p2 = (c & 63) >> 1;
                const float sc = (cls == 0) ? 0.125f : 1.f;
                bf16_t* row = ((cls == 0) ? Qo : Ko) + cq + t0 * 1024;
                const float4 cc = *(const float4*)(fcosT + p2 * 2048 + s0);
                const float4 ss = *(const float4*)(fsinT + p2 * 2048 + s0);
                const float v0 = acc[ai][nj][0], pv0 = __shfl_xor(acc[ai][nj][0], 1);
                const float v1 = acc[ai][nj][1], pv1 = __shfl_xor(acc[ai][nj][1], 1);
                const float v2 = acc[ai][nj][2], pv2 = __shfl_xor(acc[ai][nj][2], 1);
                const float v3 = acc[ai][nj][3], pv3 = __shfl_xor(acc[ai][nj][3], 1);
                row[0]    = (bf16_t)((v0 * cc.x + sgn * (pv0 * ss.x)) * sc);
                row[1024] = (bf16_t)((v1 * cc.y + sgn * (pv1 * ss.y)) * sc);
                row[2048] = (bf16_t)((v2 * cc.z + sgn * (pv2 * ss.z)) * sc);
                row[3072] = (bf16_t)((v3 * cc.w + sgn * (pv3 * ss.w)) * sc);
            }
        }
    }
}

// ---------------------------------------------------------------------------
// 256x128 GEMM (O-proj: N=1024 -> 256 blocks = 1 exact round).
// Triple-buffered deep prefetch, counted vmcnt (R3/R4 version).
// ---------------------------------------------------------------------------
template <typename OUT>
__global__ __launch_bounds__(512, 2) void gemm256(const bf16_t* __restrict__ A,
                                                  const bf16_t* __restrict__ Bw,
                                                  OUT* __restrict__ C,
                                                  int M, int N, int K) {
    __shared__ __attribute__((aligned(16))) bf16_t As[49152];   // 3 x 2 x 128x64
    __shared__ __attribute__((aligned(16))) bf16_t Bs[24576];   // 3 x 128x64
    const int tid = threadIdx.x;
    const int l = tid & 63, w = tid >> 6;
    const int lr = l & 15, lg = l >> 4;
    const int wr = w >> 1, wc = w & 1;

    const int nwg = gridDim.x * gridDim.y;
    const int flat = blockIdx.y * gridDim.x + blockIdx.x;
    const int swz = (flat & 7) * (nwg >> 3) + (flat >> 3);
    const int bx = swz % gridDim.x, by = swz / gridDim.x;
    const long m0 = (long)by * 256, n0 = (long)bx * 128;
    const int NT = K >> 6;

    int rS[2], cS[2];
#pragma unroll
    for (int i = 0; i < 2; ++i) {
        const int p  = i * 8192 + w * 1024 + l * 16;
        const int pp = p ^ (((p >> 9) & 1) << 5);
        const int st = pp >> 10;
        rS[i] = (st >> 1) * 16 + ((pp >> 6) & 15);
        cS[i] = (st & 1) * 32 + ((pp >> 4) & 3) * 8;
    }
    const bf16_t* aSrc0 = A  + (m0 + rS[0]) * K + cS[0];
    const bf16_t* aSrc1 = A  + (m0 + rS[1]) * K + cS[1];
    const bf16_t* bSrc0 = Bw + (n0 + rS[0]) * K + cS[0];
    const bf16_t* bSrc1 = Bw + (n0 + rS[1]) * K + cS[1];
    const long hK = 128L * K;

    auto stageA = [&](int b, int h, int t) {
        char* d = (char*)As + b * 32768 + h * 16384 + w * 1024;
        const long o = (long)h * hK + (long)t * 64;
        async16(aSrc0 + o, d);
        async16(aSrc1 + o, d + 8192);
    };
    auto stageB = [&](int b, int t) {
        char* d = (char*)Bs + b * 16384 + w * 1024;
        const long o = (long)t * 64;
        async16(bSrc0 + o, d);
        async16(bSrc1 + o, d + 8192);
    };

    f32x4 acc[4][4] = {};
    bf16x8 af[4][2], blo[2][2], bhi[2][2];
    const int swd = (lr & 8) << 2;

    auto loadA = [&](int b) {
#pragma unroll
        for (int mi = 0; mi < 4; ++mi)
#pragma unroll
            for (int ks = 0; ks < 2; ++ks) {
                const int ra = (wr & 1) * 64 + mi * 16 + lr;
                const int off = ((ra >> 4) * 2 + ks) * 1024 + (ra & 15) * 64 + lg * 16;
                af[mi][ks] = *(const bf16x8*)((const char*)As + b * 32768 +
                                              (wr >> 1) * 16384 + (off ^ swd));
            }
    };
    auto loadB = [&](int b, int nh, bf16x8 (&dst)[2][2]) {
#pragma unroll
        for (int nj = 0; nj < 2; ++nj)
#pragma unroll
            for (int ks = 0; ks < 2; ++ks) {
                const int rb = wc * 64 + (nh * 2 + nj) * 16 + lr;
                const int off = ((rb >> 4) * 2 + ks) * 1024 + (rb & 15) * 64 + lg * 16;
                dst[nj][ks] = *(const bf16x8*)((const char*)Bs + b * 16384 +
                                               (off ^ swd));
            }
    };

#define QMM(NH, BF) do {                                                       \
    __builtin_amdgcn_s_setprio(1);                                             \
    _Pragma("unroll")                                                          \
    for (int mi = 0; mi < 4; ++mi) {                                           \
        acc[mi][(NH)*2]   = MFMA16(af[mi][0], (BF)[0][0], acc[mi][(NH)*2]);    \
        acc[mi][(NH)*2]   = MFMA16(af[mi][1], (BF)[0][1], acc[mi][(NH)*2]);    \
        acc[mi][(NH)*2+1] = MFMA16(af[mi][0], (BF)[1][0], acc[mi][(NH)*2+1]);  \
        acc[mi][(NH)*2+1] = MFMA16(af[mi][1], (BF)[1][1], acc[mi][(NH)*2+1]);  \
    }                                                                          \
    __builtin_amdgcn_s_setprio(0);                                             \
} while (0)

    stageA(0, 0, 0); stageA(0, 1, 0); stageB(0, 0);
    stageA(1, 0, 1); stageA(1, 1, 1); stageB(1, 1);
    VMC(6);
    BAR();

    int bc = 0;
#pragma unroll 1
    for (int t = 0; t < NT - 2; ++t) {
        const int bn = (bc + 2 >= 3) ? bc - 1 : bc + 2;
        loadA(bc); loadB(bc, 0, blo); stageA(bn, 0, t + 2); stageA(bn, 1, t + 2);
        BAR(); QMM(0, blo); BAR();
        loadB(bc, 1, bhi); stageB(bn, t + 2);
        BAR(); QMM(1, bhi);
        if (t < NT - 3) { VMC(6); } else { VMC(0); }
        BAR();
        bc = (bc + 1 >= 3) ? 0 : bc + 1;
    }
    {
        loadA(bc); loadB(bc, 0, blo);
        QMM(0, blo);
        loadB(bc, 1, bhi);
        QMM(1, bhi);
        const int b2 = (bc + 1 >= 3) ? 0 : bc + 1;
        loadA(b2); loadB(b2, 0, blo);
        QMM(0, blo);
        loadB(b2, 1, bhi);
        QMM(1, bhi);
    }
#undef QMM

#pragma unroll
    for (int mi = 0; mi < 4; ++mi)
#pragma unroll
        for (int ni = 0; ni < 4; ++ni)
#pragma unroll
            for (int j = 0; j < 4; ++j) {
                long r = m0 + wr * 64 + mi * 16 + lg * 4 + j;
                long c = n0 + wc * 64 + ni * 16 + lr;
                C[r * N + c] = (OUT)acc[mi][ni][j];
            }
}

// ---------------------------------------------------------------------------
// Sliding-window attention v8: K/V LDS-staged (80 KiB, 2 blocks/CU), online
// softmax per 64-key tile, swapped QK^T, prescaled Q.  Q/K inputs are
// TOKEN-MAJOR [8192][1024] (head h at columns h*64..h*64+63).  Mask
// specialization for qt>=4 (u=0 upper-only, u=1..3 none, u=4 lower-only).
// ---------------------------------------------------------------------------
__global__ __launch_bounds__(256, 2) void attn_win4(const bf16_t* __restrict__ Q,
                                                    const bf16_t* __restrict__ Kb,
                                                    const bf16_t* __restrict__ VT,
                                                    bf16_t* __restrict__ Ao) {
    __shared__ __attribute__((aligned(16))) bf16_t kld[5 * 4096];
    __shared__ __attribute__((aligned(16))) bf16_t vld[5 * 4096];
    const int raw = blockIdx.x;
    const int mswz = ((raw & 7) << 8) | (raw >> 3);
    const int qt = mswz & 31, bh = mswz >> 5;
    const int h = bh & 15, b = bh >> 4;
    const int l = threadIdx.x & 63, w = threadIdx.x >> 6;
    const int lr = l & 15, lg = l >> 4;
    const int q0 = qt * 64 + w * 16;
    const int q = q0 + lr;
    const int tb = qt - 4;

    // token-major Q/K: row stride 1024, head h at column offset h*64
    const bf16_t* Qp = Q + (long)(b * 2048) * 1024 + h * 64;
    const bf16_t* Kp = Kb + (long)(b * 2048) * 1024 + h * 64;
    const bf16_t* Vp = VT + (long)bh * 64 * 2048;

#pragma unroll
    for (int u = 0; u < 5; ++u) {
        const int kt = tb + u;
        const int kt64 = (kt < 0 ? 0 : kt) * 64;
#pragma unroll
        for (int part = 0; part < 2; ++part) {
            const int seg = w * 2 + part;
            const int r = seg * 8 + (l >> 3);
            const int sc = (l & 7) ^ ((r >> 1) & 7);
            async16(Kp + (long)(kt64 + r) * 1024 + sc * 8,
                    (char*)kld + u * 8192 + seg * 1024);
            async16(Vp + (long)r * 2048 + kt64 + sc * 8,
                    (char*)vld + u * 8192 + seg * 1024);
        }
    }

    const bf16x8 qb0 = *(const bf16x8*)&Qp[(long)q * 1024 + lg * 8];
    const bf16x8 qb1 = *(const bf16x8*)&Qp[(long)q * 1024 + 32 + lg * 8];

    __syncthreads();

    float mrun = -1000.f, lsum = 0.f;
    f32x4 o0 = {0.f, 0.f, 0.f, 0.f}, o1 = {0.f, 0.f, 0.f, 0.f};
    f32x4 o2 = {0.f, 0.f, 0.f, 0.f}, o3 = {0.f, 0.f, 0.f, 0.f};
    const int swv = (lr >> 1) & 7;

    const char* kbase;
    const char* vbase;
    int k0s;

#define QKCORE(HH, MM)                                                           \
        const int row_ = (HH) * 32 + 2 * lr + (MM);                              \
        const int sw_ = (row_ >> 1) & 7;                                         \
        bf16x8 k0_ = *(const bf16x8*)(kbase + row_ * 128 + ((lg ^ sw_) << 4));   \
        bf16x8 k1_ = *(const bf16x8*)(kbase + row_ * 128 + (((4 + lg) ^ sw_) << 4)); \
        f32x4 s_ = {0.f, 0.f, 0.f, 0.f};                                         \
        s_ = MFMA16(k0_, qb0, s_);                                               \
        s_ = MFMA16(k1_, qb1, s_);

#define QKF_F(DST, HH, MM)                                                       \
    f32x4 DST; { QKCORE(HH, MM)                                                  \
        const int kb_ = k0s + (HH) * 32 + (MM) + lg * 8;                         \
        DST[0] = ((kb_ >= 0) & ((unsigned)(q - kb_) < 256u))         ? s_[0] : -1e30f; \
        DST[1] = ((kb_ + 2 >= 0) & ((unsigned)(q - kb_ - 2) < 256u)) ? s_[1] : -1e30f; \
        DST[2] = ((kb_ + 4 >= 0) & ((unsigned)(q - kb_ - 4) < 256u)) ? s_[2] : -1e30f; \
        DST[3] = ((kb_ + 6 >= 0) & ((unsigned)(q - kb_ - 6) < 256u)) ? s_[3] : -1e30f; \
    }

#define QKF_U(DST, HH, MM)                                                       \
    f32x4 DST; { QKCORE(HH, MM)                                                  \
        const int d_ = q - (k0s + (HH) * 32 + (MM) + lg * 8);                    \
        DST[0] = (d_ < 256)     ? s_[0] : -1e30f;                                \
        DST[1] = (d_ - 2 < 256) ? s_[1] : -1e30f;                                \
        DST[2] = (d_ - 4 < 256) ? s_[2] : -1e30f;                                \
        DST[3] = (d_ - 6 < 256) ? s_[3] : -1e30f;                                \
    }

#define QKF_L(DST, HH, MM)                                                       \
    f32x4 DST; { QKCORE(HH, MM)                                                  \
        const int d_ = q - (k0s + (HH) * 32 + (MM) + lg * 8);                    \
        DST[0] = (d_ >= 0)     ? s_[0] : -1e30f;                                 \
        DST[1] = (d_ - 2 >= 0) ? s_[1] : -1e30f;                                 \
        DST[2] = (d_ - 4 >= 0) ? s_[2] : -1e30f;                                 \
        DST[3] = (d_ - 6 >= 0) ? s_[3] : -1e30f;                                 \
    }

#define QKF_N(DST, HH, MM)                                                       \
    f32x4 DST; { QKCORE(HH, MM)                                                  \
        DST[0] = s_[0]; DST[1] = s_[1]; DST[2] = s_[2]; DST[3] = s_[3];          \
    }

#define EXV(S_) {                                                                \
        S_[0] = __expf(S_[0] - mnew); S_[1] = __expf(S_[1] - mnew);              \
        S_[2] = __expf(S_[2] - mnew); S_[3] = __expf(S_[3] - mnew);              \
        rs += (S_[0] + S_[1]) + (S_[2] + S_[3]); }

#define PVF(NT, HH, PB) {                                                        \
        bf16x8 va_ = *(const bf16x8*)(vbase + ((NT) * 16 + lr) * 128 +           \
                                      ((((HH) * 4 + lg) ^ swv) << 4));           \
        o##NT = MFMA16(va_, PB, o##NT); }

#define TILEBODY(QKM) {                                                          \
        QKM(sA, 0, 0) QKM(sB, 0, 1) QKM(sC, 1, 0) QKM(sD, 1, 1)                  \
        float tm = fmaxf(fmaxf(fmaxf(sA[0], sA[1]), fmaxf(sA[2], sA[3])),        \
                         fmaxf(fmaxf(sB[0], sB[1]), fmaxf(sB[2], sB[3])));       \
        tm = fmaxf(tm, fmaxf(fmaxf(fmaxf(sC[0], sC[1]), fmaxf(sC[2], sC[3])),    \
                             fmaxf(fmaxf(sD[0], sD[1]), fmaxf(sD[2], sD[3]))));  \
        tm = fmaxf(tm, __shfl_xor(tm, 16));                                      \
        tm = fmaxf(tm, __shfl_xor(tm, 32));                                      \
        const float mnew = fmaxf(mrun, tm);                                      \
        const float alpha = __expf(mrun - mnew);                                 \
        mrun = mnew;                                                             \
        float rs = 0.f;                                                          \
        EXV(sA) EXV(sB) EXV(sC) EXV(sD)                                          \
        rs += __shfl_xor(rs, 16);                                                \
        rs += __shfl_xor(rs, 32);                                                \
        lsum = lsum * alpha + rs;                                                \
        o0[0] *= alpha; o0[1] *= alpha; o0[2] *= alpha; o0[3] *= alpha;          \
        o1[0] *= alpha; o1[1] *= alpha; o1[2] *= alpha; o1[3] *= alpha;          \
        o2[0] *= alpha; o2[1] *= alpha; o2[2] *= alpha; o2[3] *= alpha;          \
        o3[0] *= alpha; o3[1] *= alpha; o3[2] *= alpha; o3[3] *= alpha;          \
        bf16x8 pb0, pb1;                                                         \
        pb0[0] = (bf16_t)sA[0]; pb0[1] = (bf16_t)sA[1]; pb0[2] = (bf16_t)sA[2]; pb0[3] = (bf16_t)sA[3]; \
        pb0[4] = (bf16_t)sB[0]; pb0[5] = (bf16_t)sB[1]; pb0[6] = (bf16_t)sB[2]; pb0[7] = (bf16_t)sB[3]; \
        pb1[0] = (bf16_t)sC[0]; pb1[1] = (bf16_t)sC[1]; pb1[2] = (bf16_t)sC[2]; pb1[3] = (bf16_t)sC[3]; \
        pb1[4] = (bf16_t)sD[0]; pb1[5] = (bf16_t)sD[1]; pb1[6] = (bf16_t)sD[2]; pb1[7] = (bf16_t)sD[3]; \
        PVF(0, 0, pb0) PVF(1, 0, pb0) PVF(2, 0, pb0) PVF(3, 0, pb0)              \
        PVF(0, 1, pb1) PVF(1, 1, pb1) PVF(2, 1, pb1) PVF(3, 1, pb1)              \
    }

#define SETT(U) kbase = (const char*)kld + (U) * 8192;                           \
                vbase = (const char*)vld + (U) * 8192;                           \
                k0s = (tb + (U)) * 64;

    if (qt >= 4) {
        SETT(0) TILEBODY(QKF_U)
        SETT(1) TILEBODY(QKF_N)
        SETT(2) TILEBODY(QKF_N)
        SETT(3) TILEBODY(QKF_N)
        SETT(4) TILEBODY(QKF_L)
    } else {
#pragma unroll
        for (int u = 0; u < 5; ++u) {
            SETT(u) TILEBODY(QKF_F)
        }
    }
#undef SETT
#undef TILEBODY
#undef QKF_F
#undef QKF_U
#undef QKF_L
#undef QKF_N
#undef QKCORE
#undef EXV
#undef PVF

    const float rinv = 1.0f / lsum;
    bf16_t* aor = Ao + ((long)(b * 2048) + q) * 1024 + h * 64;
#define EPI(NT, OA_) {                                                           \
        bf16x4 ov_;                                                             \
        ov_[0] = (bf16_t)(OA_[0] * rinv); ov_[1] = (bf16_t)(OA_[1] * rinv);      \
        ov_[2] = (bf16_t)(OA_[2] * rinv); ov_[3] = (bf16_t)(OA_[3] * rinv);      \
        *(bf16x4*)(aor + (NT) * 16 + lg * 4) = ov_; }
    EPI(0, o0) EPI(1, o1) EPI(2, o2) EPI(3, o3)
#undef EPI
}

// ---------------------------------------------------------------------------
extern "C" void kernel_launch(void* const* d_in, const int* in_sizes, int n_in,
                              void* d_out, int out_size, void* d_ws, size_t ws_size,
                              hipStream_t stream) {
    (void)in_sizes; (void)n_in; (void)out_size; (void)ws_size;
    const float* x    = (const float*)d_in[0];
    const float* fcos = (const float*)d_in[1];
    const float* fsin = (const float*)d_in[2];
    const float* wq   = (const float*)d_in[3];
    const float* wk   = (const float*)d_in[4];
    const float* wv   = (const float*)d_in[5];
    const float* wo   = (const float*)d_in[6];
    float* out = (float*)d_out;

    char* ws = (char*)d_ws;
    // layout (bytes): xbf 16MB @0 | wqkv 6MB @16M | wobf 2MB @22M |
    //                 fcosT 256KB @24M | fsinT 256KB | qbuf 16MB @40M |
    //                 kbuf 16MB @72M | vtb 16MB @88M. aob reuses xbf.
    bf16_t* xbf   = (bf16_t*)(ws);
    bf16_t* wqkv  = (bf16_t*)(ws + 16777216);
    bf16_t* wobf  = (bf16_t*)(ws + 23068672);
    float*  fcosT = (float*)(ws + 25165824);
    float*  fsinT = (float*)(ws + 25427968);
    bf16_t* qbuf  = (bf16_t*)(ws + 41943040);
    bf16_t* kbuf  = (bf16_t*)(ws + 75497472);
    bf16_t* vtb   = (bf16_t*)(ws + 92274688);
    bf16_t* aob   = xbf;   // xbf dead after gemm192_qkv

    cvt_all<<<6176, 256, 0, stream>>>(x, wq, wk, wv, wo, fcos, fsin,
                                      xbf, wqkv, wobf, fcosT, fsinT);

    // QKV + fused RoPE/layout/V-transpose: (16,32) = 512 blocks = 2 rounds
    gemm192_qkv<<<dim3(16, 32), 512, 0, stream>>>(xbf, wqkv, fcosT, fsinT,
                                                  qbuf, kbuf, vtb,
                                                  8192, 3072, 1024);
    attn_win4<<<2048, 256, 0, stream>>>(qbuf, kbuf, vtb, aob);
    // O-proj: grid (8, 32) = 256 blocks = 1 exact round
    gemm256<float><<<dim3(8, 32), 512, 0, stream>>>(aob, wobf, out, 8192, 1024, 1024);
}

// Round 13
// 124.392 us; speedup vs baseline: 1.0264x; 1.0264x over previous
//
#include <hip/hip_runtime.h>
#include <hip/hip_bf16.h>

// ---------------------------------------------------------------------------
// Sliding-window attention (B=4,S=2048,D=1024,H=16,HD=64,W=256) on gfx950.
// Pipeline: cvt(all) -> GEMM(QKV, 256x192 8-phase, FUSED epilogue: Q/K/V all
//           through per-wave LDS transpose; in-lane RoPE (+0.125 prescale on
//           Q); wide 16B stores; token-major Q/K [8192][1024], VT[bh][64][2048])
//           -> flash window attn (K+V LDS-staged) -> GEMM(O-proj, 256x128).
// ---------------------------------------------------------------------------

typedef __bf16 bf16_t;
typedef __attribute__((ext_vector_type(8))) __bf16 bf16x8;
typedef __attribute__((ext_vector_type(4))) __bf16 bf16x4;
typedef __attribute__((ext_vector_type(4))) float f32x4;

#define MFMA16(a, b, c) __builtin_amdgcn_mfma_f32_16x16x32_bf16((a), (b), (c), 0, 0, 0)

// async global->LDS, 16 bytes per lane. LDS dest is wave-uniform base + lane*16.
__device__ __forceinline__ void async16(const void* g, void* l) {
    __builtin_amdgcn_global_load_lds(
        (const __attribute__((address_space(1))) unsigned int*)g,
        (__attribute__((address_space(3))) unsigned int*)l, 16, 0, 0);
}

#define BAR() do { asm volatile("" ::: "memory"); __builtin_amdgcn_s_barrier(); \
                   asm volatile("" ::: "memory"); } while (0)
#define VMC(N) asm volatile("s_waitcnt vmcnt(" #N ")" ::: "memory")
#define LGKM0() asm volatile("s_waitcnt lgkmcnt(0)" ::: "memory")

// ---------------------------------------------------------------------------
// Fused f32 -> bf16 convert for all 5 tensors, 8 elems/thread.
// ---------------------------------------------------------------------------
__global__ __launch_bounds__(256) void cvt_all(const float* __restrict__ x,
                                               const float* __restrict__ wq,
                                               const float* __restrict__ wk,
                                               const float* __restrict__ wv,
                                               const float* __restrict__ wo,
                                               bf16_t* __restrict__ xbf,
                                               bf16_t* __restrict__ wqkv,
                                               bf16_t* __restrict__ wobf) {
    const int blk = blockIdx.x;
    const float* s;
    bf16_t* d;
    int base;
    if (blk < 4096)      { s = x;  d = xbf;            base = blk; }
    else if (blk < 4608) { s = wq; d = wqkv;           base = blk - 4096; }
    else if (blk < 5120) { s = wk; d = wqkv + 1048576; base = blk - 4608; }
    else if (blk < 5632) { s = wv; d = wqkv + 2097152; base = blk - 5120; }
    else                 { s = wo; d = wobf;           base = blk - 5632; }
    const int i = (base * 256 + threadIdx.x) * 8;
    float4 a = *(const float4*)(s + i);
    float4 b = *(const float4*)(s + i + 4);
    bf16x8 o;
    o[0] = (bf16_t)a.x; o[1] = (bf16_t)a.y; o[2] = (bf16_t)a.z; o[3] = (bf16_t)a.w;
    o[4] = (bf16_t)b.x; o[5] = (bf16_t)b.y; o[6] = (bf16_t)b.z; o[7] = (bf16_t)b.w;
    *(bf16x8*)(d + i) = o;
}

// ---------------------------------------------------------------------------
// 256x192 8-phase QKV GEMM with FUSED epilogue (R13).
// Main loop identical to R4/R6 (counted vmcnt, st_16x32 swizzle, 8 waves).
// Epilogue: EVERY fragment (16 ch x 128 tok) goes through a per-wave LDS
// transpose (scr[tok][ch], stride 20 bf16 -> 8B-aligned b64 reads, ~2-way
// banks).  After transpose each lane holds 8 consecutive channels of one
// token:
//   q/k: RoPE pairs fully IN-LANE (no shuffles); cos/sin = one float4 from
//        the original s-major tables; one bf16x8 (16B) store per item ->
//        4 wide stores/fragment vs 32 scalar.  Q prescaled by 0.125.
//        (Numerics = pre-R7 pipeline: RoPE on bf16-rounded GEMM output.)
//   v:   within-8 key permutation readback -> VT[bh][64][2048] (as before).
// Scratch safety: buf0 of As/Bs free after the VMC(0)+BAR before the last
// tile; regions per-wave private; same-wave DS ops are in-order + LGKM0.
// ---------------------------------------------------------------------------
__global__ __launch_bounds__(512, 1) __attribute__((amdgpu_waves_per_eu(2)))
void gemm192_qkv(const bf16_t* __restrict__ A, const bf16_t* __restrict__ Bw,
                 const float* __restrict__ fcos, const float* __restrict__ fsin,
                 bf16_t* __restrict__ Qo, bf16_t* __restrict__ Ko,
                 bf16_t* __restrict__ VT, int M, int N, int K) {
    __shared__ __attribute__((aligned(16))) bf16_t As[32768];   // 2 x 4u x 8KiB
    __shared__ __attribute__((aligned(16))) bf16_t Bs[24576];   // 2 x 3u x 8KiB
    const int tid = threadIdx.x;
    const int l = tid & 63, w = tid >> 6;
    const int lr = l & 15, lg = l >> 4;
    const int wr = w >> 2, wc = w & 3;          // 2M x 4N

    const int nwg = gridDim.x * gridDim.y;
    const int flat = blockIdx.y * gridDim.x + blockIdx.x;
    const int swz = (flat & 7) * (nwg >> 3) + (flat >> 3);
    const int bx = swz % gridDim.x, by = swz / gridDim.x;
    const long m0 = (long)by * 256, n0 = (long)bx * 192;
    const int NT = K >> 6;
    const int NI = NT >> 1;

    const int p  = w * 1024 + l * 16;
    const int pp = p ^ (((p >> 9) & 1) << 5);
    const int st = pp >> 10;
    const int rSt = (st >> 1) * 16 + ((pp >> 6) & 15);
    const int cSt = (st & 1) * 32 + ((pp >> 4) & 3) * 8;
    const bf16_t* aS = A  + (m0 + rSt) * K + cSt;
    const bf16_t* bS = Bw + (n0 + rSt) * K + cSt;
    const long uK = 64L * K;

    auto stageA = [&](int b, int u, int t) {
        async16(aS + (long)u * uK + (long)t * 64,
                (char*)As + b * 32768 + u * 8192 + w * 1024);
    };
    auto stageB = [&](int b, int u, int t) {
        async16(bS + (long)u * uK + (long)t * 64,
                (char*)Bs + b * 24576 + u * 8192 + w * 1024);
    };

    f32x4 acc[8][3] = {};
    bf16x8 afX[4], afY[4], bfX[3], bfY[3];
    const int swd = (lr & 8) << 2;

    auto loadAF = [&](int b, int mh, int ks, bf16x8 (&dst)[4]) {
#pragma unroll
        for (int mi = 0; mi < 4; ++mi) {
            const int off = (wr * 2 + mh) * 8192 + (mi * 2 + ks) * 1024 +
                            lr * 64 + lg * 16;
            dst[mi] = *(const bf16x8*)((const char*)As + b * 32768 + (off ^ swd));
        }
    };
    auto loadBF = [&](int b, int ks, bf16x8 (&dst)[3]) {
#pragma unroll
        for (int nj = 0; nj < 3; ++nj) {
            const int rg = wc * 48 + nj * 16 + lr;
            const int off = (rg >> 6) * 8192 + (((rg >> 4) & 3) * 2 + ks) * 1024 +
                            lr * 64 + lg * 16;
            dst[nj] = *(const bf16x8*)((const char*)Bs + b * 24576 + (off ^ swd));
        }
    };

#define QMM(MH, AF, BF) do {                                                   \
    __builtin_amdgcn_s_setprio(1);                                             \
    _Pragma("unroll")                                                          \
    for (int mi = 0; mi < 4; ++mi)                                             \
        _Pragma("unroll")                                                      \
        for (int nj = 0; nj < 3; ++nj)                                         \
            acc[(MH)*4+mi][nj] = MFMA16((AF)[mi], (BF)[nj], acc[(MH)*4+mi][nj]); \
    __builtin_amdgcn_s_setprio(0);                                             \
} while (0)

    // ---- prologue ----
    stageA(0, 0, 0); stageA(0, 1, 0); stageA(0, 2, 0); stageA(0, 3, 0);
    stageB(0, 0, 0); stageB(0, 1, 0); stageB(0, 2, 0);
    stageB(1, 0, 1); stageB(1, 1, 1); stageB(1, 2, 1);
    VMC(3);
    BAR();

#pragma unroll 1
    for (int it = 0; it < NI - 1; ++it) {
        const int T = 2 * it;
        loadAF(0, 0, 0, afX); loadBF(0, 0, bfX);
        stageA(1, 0, T + 1); stageA(1, 1, T + 1);
        BAR(); QMM(0, afX, bfX); BAR();
        loadAF(0, 1, 0, afY);
        stageA(1, 2, T + 1); stageA(1, 3, T + 1);
        BAR(); QMM(1, afY, bfX); BAR();
        loadAF(0, 0, 1, afX); loadBF(0, 1, bfY);
        BAR(); QMM(0, afX, bfY); BAR();
        loadAF(0, 1, 1, afY);
        stageB(0, 0, T + 2);
        BAR(); QMM(1, afY, bfY); VMC(1); BAR();
        loadAF(1, 0, 0, afX); loadBF(1, 0, bfX);
        stageB(0, 1, T + 2); stageB(0, 2, T + 2);
        BAR(); QMM(0, afX, bfX); BAR();
        loadAF(1, 1, 0, afY);
        stageA(0, 0, T + 2); stageA(0, 1, T + 2);
        BAR(); QMM(1, afY, bfX); BAR();
        loadAF(1, 0, 1, afX); loadBF(1, 1, bfY);
        stageA(0, 2, T + 2); stageA(0, 3, T + 2);
        BAR(); QMM(0, afX, bfY); BAR();
        loadAF(1, 1, 1, afY);
        stageB(1, 0, T + 3); stageB(1, 1, T + 3); stageB(1, 2, T + 3);
        BAR(); QMM(1, afY, bfY); VMC(3); BAR();
    }

    // ---- final iteration (tiles NT-2 buf0, NT-1 buf1) ----
    {
        loadAF(0, 0, 0, afX); loadBF(0, 0, bfX);
        stageA(1, 0, NT - 1); stageA(1, 1, NT - 1);
        BAR(); QMM(0, afX, bfX); BAR();
        loadAF(0, 1, 0, afY);
        stageA(1, 2, NT - 1); stageA(1, 3, NT - 1);
        BAR(); QMM(1, afY, bfX); BAR();
        loadAF(0, 0, 1, afX); loadBF(0, 1, bfY);
        BAR(); QMM(0, afX, bfY); BAR();
        loadAF(0, 1, 1, afY);
        BAR(); QMM(1, afY, bfY);
        VMC(0); BAR();                 // <- after this, buf0 of As/Bs is free
        loadAF(1, 0, 0, afX); loadBF(1, 0, bfX);
        QMM(0, afX, bfX);
        loadAF(1, 1, 0, afY);
        QMM(1, afY, bfX);
        loadAF(1, 0, 1, afX); loadBF(1, 1, bfY);
        QMM(0, afX, bfY);
        loadAF(1, 1, 1, afY);
        QMM(1, afY, bfY);
    }
#undef QMM

    // ---- FUSED epilogue ----
    // per-wave private scratch in buf0 (free): 128 tok x 20 bf16 = 5120 B.
    // waves 0-5 in As (6*5120 = 30720 <= 32768), waves 6-7 in Bs.
    bf16_t* scr = (w < 6) ? (bf16_t*)((char*)As + w * 5120)
                          : (bf16_t*)((char*)Bs + (w - 6) * 5120);
    asm volatile("" ::: "memory");

    const int tl = l & 31, cg = l >> 5;          // readback lane mapping
    const int chb = cg * 8;                      // channel group base 0/8

#pragma unroll
    for (int nj = 0; nj < 3; ++nj) {
        const int cbase = (int)n0 + wc * 48 + nj * 16;   // multiple of 16
        const int cls = cbase >> 10;                     // 0=q,1=k,2=v (uniform)

        // transpose this fragment: scr[token][channel] (bf16, stride 20)
#pragma unroll
        for (int ai = 0; ai < 8; ++ai)
#pragma unroll
            for (int j = 0; j < 4; ++j)
                scr[(ai * 16 + lg * 4 + j) * 20 + lr] = (bf16_t)acc[ai][nj][j];
        LGKM0();
        asm volatile("" ::: "memory");

        if (cls == 2) {
            // ---- V: within-8 key perm readback -> VT, 64B-line friendly ----
            const int ch = l >> 2;                       // channel 0..15
            const int sub = l & 3;                       // 16B chunk within 64B
            const int d16 = cbase - 2048 + ch;
            const int hh = d16 >> 6, dd = d16 & 63;
            const long T0 = m0 + wr * 128;
            const int bb = (int)(T0 >> 11);
            const int s0 = (int)(T0 & 2047);
            bf16_t* vrow = VT + ((long)((bb * 16 + hh) * 64 + dd) * 2048) + s0;
#pragma unroll
            for (int qq = 0; qq < 4; ++qq) {
                const int tb8 = qq * 32 + sub * 8;       // token base of chunk
                bf16x8 o;
#pragma unroll
                for (int j = 0; j < 8; ++j) {
                    const int f = ((j & 3) << 1) | (j >> 2);  // pos j holds key f
                    o[j] = scr[(tb8 + f) * 20 + ch];
                }
                *(bf16x8*)(vrow + tb8) = o;
            }
        } else {
            // ---- Q/K: in-lane RoPE on 8 consecutive channels, 16B store ----
            const int cq = cbase & 1023;
            const float sc = (cls == 0) ? 0.125f : 1.f;
            bf16_t* qk = ((cls == 0) ? Qo : Ko) + cq + chb;
            const int p2b = ((cbase & 63) >> 1) + cg * 4;  // 4-aligned
#pragma unroll
            for (int qq = 0; qq < 4; ++qq) {
                const int t = tl + qq * 32;              // token 0..127
                bf16x4 vlo = *(const bf16x4*)&scr[t * 20 + chb];
                bf16x4 vhi = *(const bf16x4*)&scr[t * 20 + chb + 4];
                const long gt = m0 + wr * 128 + t;
                const int s0 = (int)(gt & 2047);
                const float4 cc = *(const float4*)(fcos + s0 * 32 + p2b);
                const float4 sn = *(const float4*)(fsin + s0 * 32 + p2b);
                bf16x8 o;
                float e0, e1;
                e0 = (float)vlo[0]; e1 = (float)vlo[1];
                o[0] = (bf16_t)((e0 * cc.x - e1 * sn.x) * sc);
                o[1] = (bf16_t)((e0 * sn.x + e1 * cc.x) * sc);
                e0 = (float)vlo[2]; e1 = (float)vlo[3];
                o[2] = (bf16_t)((e0 * cc.y - e1 * sn.y) * sc);
                o[3] = (bf16_t)((e0 * sn.y + e1 * cc.y) * sc);
                e0 = (float)vhi[0]; e1 = (float)vhi[1];
                o[4] = (bf16_t)((e0 * cc.z - e1 * sn.z) * sc);
                o[5] = (bf16_t)((e0 * sn.z + e1 * cc.z) * sc);
                e0 = (float)vhi[2]; e1 = (float)vhi[3];
                o[6] = (bf16_t)((e0 * cc.w - e1 * sn.w) * sc);
                o[7] = (bf16_t)((e0 * sn.w + e1 * cc.w) * sc);
                *(bf16x8*)(qk + gt * 1024) = o;
            }
        }
        LGKM0();                       // all reads of scr done before reuse
        asm volatile("" ::: "memory");
    }
}

// ---------------------------------------------------------------------------
// 256x128 GEMM (O-proj: N=1024 -> 256 blocks = 1 exact round).
// Triple-buffered deep prefetch, counted vmcnt (R3/R4 version).
// ---------------------------------------------------------------------------
template <typename OUT>
__global__ __launch_bounds__(512, 2) void gemm256(const bf16_t* __restrict__ A,
                                                  const bf16_t* __restrict__ Bw,
                                                  OUT* __restrict__ C,
                                                  int M, int N, int K) {
    __shared__ __attribute__((aligned(16))) bf16_t As[49152];   // 3 x 2 x 128x64
    __shared__ __attribute__((aligned(16))) bf16_t Bs[24576];   // 3 x 128x64
    const int tid = threadIdx.x;
    const int l = tid & 63, w = tid >> 6;
    const int lr = l & 15, lg = l >> 4;
    const int wr = w >> 1, wc = w & 1;

    const int nwg = gridDim.x * gridDim.y;
    const int flat = blockIdx.y * gridDim.x + blockIdx.x;
    const int swz = (flat & 7) * (nwg >> 3) + (flat >> 3);
    const int bx = swz % gridDim.x, by = swz / gridDim.x;
    const long m0 = (long)by * 256, n0 = (long)bx * 128;
    const int NT = K >> 6;

    int rS[2], cS[2];
#pragma unroll
    for (int i = 0; i < 2; ++i) {
        const int p  = i * 8192 + w * 1024 + l * 16;
        const int pp = p ^ (((p >> 9) & 1) << 5);
        const int st = pp >> 10;
        rS[i] = (st >> 1) * 16 + ((pp >> 6) & 15);
        cS[i] = (st & 1) * 32 + ((pp >> 4) & 3) * 8;
    }
    const bf16_t* aSrc0 = A  + (m0 + rS[0]) * K + cS[0];
    const bf16_t* aSrc1 = A  + (m0 + rS[1]) * K + cS[1];
    const bf16_t* bSrc0 = Bw + (n0 + rS[0]) * K + cS[0];
    const bf16_t* bSrc1 = Bw + (n0 + rS[1]) * K + cS[1];
    const long hK = 128L * K;

    auto stageA = [&](int b, int h, int t) {
        char* d = (char*)As + b * 32768 + h * 16384 + w * 1024;
        const long o = (long)h * hK + (long)t * 64;
        async16(aSrc0 + o, d);
        async16(aSrc1 + o, d + 8192);
    };
    auto stageB = [&](int b, int t) {
        char* d = (char*)Bs + b * 16384 + w * 1024;
        const long o = (long)t * 64;
        async16(bSrc0 + o, d);
        async16(bSrc1 + o, d + 8192);
    };

    f32x4 acc[4][4] = {};
    bf16x8 af[4][2], blo[2][2], bhi[2][2];
    const int swd = (lr & 8) << 2;

    auto loadA = [&](int b) {
#pragma unroll
        for (int mi = 0; mi < 4; ++mi)
#pragma unroll
            for (int ks = 0; ks < 2; ++ks) {
                const int ra = (wr & 1) * 64 + mi * 16 + lr;
                const int off = ((ra >> 4) * 2 + ks) * 1024 + (ra & 15) * 64 + lg * 16;
                af[mi][ks] = *(const bf16x8*)((const char*)As + b * 32768 +
                                              (wr >> 1) * 16384 + (off ^ swd));
            }
    };
    auto loadB = [&](int b, int nh, bf16x8 (&dst)[2][2]) {
#pragma unroll
        for (int nj = 0; nj < 2; ++nj)
#pragma unroll
            for (int ks = 0; ks < 2; ++ks) {
                const int rb = wc * 64 + (nh * 2 + nj) * 16 + lr;
                const int off = ((rb >> 4) * 2 + ks) * 1024 + (rb & 15) * 64 + lg * 16;
                dst[nj][ks] = *(const bf16x8*)((const char*)Bs + b * 16384 +
                                               (off ^ swd));
            }
    };

#define QMM(NH, BF) do {                                                       \
    __builtin_amdgcn_s_setprio(1);                                             \
    _Pragma("unroll")                                                          \
    for (int mi = 0; mi < 4; ++mi) {                                           \
        acc[mi][(NH)*2]   = MFMA16(af[mi][0], (BF)[0][0], acc[mi][(NH)*2]);    \
        acc[mi][(NH)*2]   = MFMA16(af[mi][1], (BF)[0][1], acc[mi][(NH)*2]);    \
        acc[mi][(NH)*2+1] = MFMA16(af[mi][0], (BF)[1][0], acc[mi][(NH)*2+1]);  \
        acc[mi][(NH)*2+1] = MFMA16(af[mi][1], (BF)[1][1], acc[mi][(NH)*2+1]);  \
    }                                                                          \
    __builtin_amdgcn_s_setprio(0);                                             \
} while (0)

    stageA(0, 0, 0); stageA(0, 1, 0); stageB(0, 0);
    stageA(1, 0, 1); stageA(1, 1, 1); stageB(1, 1);
    VMC(6);
    BAR();

    int bc = 0;
#pragma unroll 1
    for (int t = 0; t < NT - 2; ++t) {
        const int bn = (bc + 2 >= 3) ? bc - 1 : bc + 2;
        loadA(bc); loadB(bc, 0, blo); stageA(bn, 0, t + 2); stageA(bn, 1, t + 2);
        BAR(); QMM(0, blo); BAR();
        loadB(bc, 1, bhi); stageB(bn, t + 2);
        BAR(); QMM(1, bhi);
        if (t < NT - 3) { VMC(6); } else { VMC(0); }
        BAR();
        bc = (bc + 1 >= 3) ? 0 : bc + 1;
    }
    {
        loadA(bc); loadB(bc, 0, blo);
        QMM(0, blo);
        loadB(bc, 1, bhi);
        QMM(1, bhi);
        const int b2 = (bc + 1 >= 3) ? 0 : bc + 1;
        loadA(b2); loadB(b2, 0, blo);
        QMM(0, blo);
        loadB(b2, 1, bhi);
        QMM(1, bhi);
    }
#undef QMM

#pragma unroll
    for (int mi = 0; mi < 4; ++mi)
#pragma unroll
        for (int ni = 0; ni < 4; ++ni)
#pragma unroll
            for (int j = 0; j < 4; ++j) {
                long r = m0 + wr * 64 + mi * 16 + lg * 4 + j;
                long c = n0 + wc * 64 + ni * 16 + lr;
                C[r * N + c] = (OUT)acc[mi][ni][j];
            }
}

// ---------------------------------------------------------------------------
// Sliding-window attention v8: K/V LDS-staged (80 KiB, 2 blocks/CU), online
// softmax per 64-key tile, swapped QK^T, prescaled Q.  Q/K inputs are
// TOKEN-MAJOR [8192][1024] (head h at columns h*64..h*64+63).  Mask
// specialization for qt>=4 (u=0 upper-only, u=1..3 none, u=4 lower-only).
// ---------------------------------------------------------------------------
__global__ __launch_bounds__(256, 2) void attn_win4(const bf16_t* __restrict__ Q,
                                                    const bf16_t* __restrict__ Kb,
                                                    const bf16_t* __restrict__ VT,
                                                    bf16_t* __restrict__ Ao) {
    __shared__ __attribute__((aligned(16))) bf16_t kld[5 * 4096];
    __shared__ __attribute__((aligned(16))) bf16_t vld[5 * 4096];
    const int raw = blockIdx.x;
    const int mswz = ((raw & 7) << 8) | (raw >> 3);
    const int qt = mswz & 31, bh = mswz >> 5;
    const int h = bh & 15, b = bh >> 4;
    const int l = threadIdx.x & 63, w = threadIdx.x >> 6;
    const int lr = l & 15, lg = l >> 4;
    const int q0 = qt * 64 + w * 16;
    const int q = q0 + lr;
    const int tb = qt - 4;

    // token-major Q/K: row stride 1024, head h at column offset h*64
    const bf16_t* Qp = Q + (long)(b * 2048) * 1024 + h * 64;
    const bf16_t* Kp = Kb + (long)(b * 2048) * 1024 + h * 64;
    const bf16_t* Vp = VT + (long)bh * 64 * 2048;

#pragma unroll
    for (int u = 0; u < 5; ++u) {
        const int kt = tb + u;
        const int kt64 = (kt < 0 ? 0 : kt) * 64;
#pragma unroll
        for (int part = 0; part < 2; ++part) {
            const int seg = w * 2 + part;
            const int r = seg * 8 + (l >> 3);
            const int sc = (l & 7) ^ ((r >> 1) & 7);
            async16(Kp + (long)(kt64 + r) * 1024 + sc * 8,
                    (char*)kld + u * 8192 + seg * 1024);
            async16(Vp + (long)r * 2048 + kt64 + sc * 8,
                    (char*)vld + u * 8192 + seg * 1024);
        }
    }

    const bf16x8 qb0 = *(const bf16x8*)&Qp[(long)q * 1024 + lg * 8];
    const bf16x8 qb1 = *(const bf16x8*)&Qp[(long)q * 1024 + 32 + lg * 8];

    __syncthreads();

    float mrun = -1000.f, lsum = 0.f;
    f32x4 o0 = {0.f, 0.f, 0.f, 0.f}, o1 = {0.f, 0.f, 0.f, 0.f};
    f32x4 o2 = {0.f, 0.f, 0.f, 0.f}, o3 = {0.f, 0.f, 0.f, 0.f};
    const int swv = (lr >> 1) & 7;

    const char* kbase;
    const char* vbase;
    int k0s;

#define QKCORE(HH, MM)                                                           \
        const int row_ = (HH) * 32 + 2 * lr + (MM);                              \
        const int sw_ = (row_ >> 1) & 7;                                         \
        bf16x8 k0_ = *(const bf16x8*)(kbase + row_ * 128 + ((lg ^ sw_) << 4));   \
        bf16x8 k1_ = *(const bf16x8*)(kbase + row_ * 128 + (((4 + lg) ^ sw_) << 4)); \
        f32x4 s_ = {0.f, 0.f, 0.f, 0.f};                                         \
        s_ = MFMA16(k0_, qb0, s_);                                               \
        s_ = MFMA16(k1_, qb1, s_);

#define QKF_F(DST, HH, MM)                                                       \
    f32x4 DST; { QKCORE(HH, MM)                                                  \
        const int kb_ = k0s + (HH) * 32 + (MM) + lg * 8;                         \
        DST[0] = ((kb_ >= 0) & ((unsigned)(q - kb_) < 256u))         ? s_[0] : -1e30f; \
        DST[1] = ((kb_ + 2 >= 0) & ((unsigned)(q - kb_ - 2) < 256u)) ? s_[1] : -1e30f; \
        DST[2] = ((kb_ + 4 >= 0) & ((unsigned)(q - kb_ - 4) < 256u)) ? s_[2] : -1e30f; \
        DST[3] = ((kb_ + 6 >= 0) & ((unsigned)(q - kb_ - 6) < 256u)) ? s_[3] : -1e30f; \
    }

#define QKF_U(DST, HH, MM)                                                       \
    f32x4 DST; { QKCORE(HH, MM)                                                  \
        const int d_ = q - (k0s + (HH) * 32 + (MM) + lg * 8);                    \
        DST[0] = (d_ < 256)     ? s_[0] : -1e30f;                                \
        DST[1] = (d_ - 2 < 256) ? s_[1] : -1e30f;                                \
        DST[2] = (d_ - 4 < 256) ? s_[2] : -1e30f;                                \
        DST[3] = (d_ - 6 < 256) ? s_[3] : -1e30f;                                \
    }

#define QKF_L(DST, HH, MM)                                                       \
    f32x4 DST; { QKCORE(HH, MM)                                                  \
        const int d_ = q - (k0s + (HH) * 32 + (MM) + lg * 8);                    \
        DST[0] = (d_ >= 0)     ? s_[0] : -1e30f;                                 \
        DST[1] = (d_ - 2 >= 0) ? s_[1] : -1e30f;                                 \
        DST[2] = (d_ - 4 >= 0) ? s_[2] : -1e30f;                                 \
        DST[3] = (d_ - 6 >= 0) ? s_[3] : -1e30f;                                 \
    }

#define QKF_N(DST, HH, MM)                                                       \
    f32x4 DST; { QKCORE(HH, MM)                                                  \
        DST[0] = s_[0]; DST[1] = s_[1]; DST[2] = s_[2]; DST[3] = s_[3];          \
    }

#define EXV(S_) {                                                                \
        S_[0] = __expf(S_[0] - mnew); S_[1] = __expf(S_[1] - mnew);              \
        S_[2] = __expf(S_[2] - mnew); S_[3] = __expf(S_[3] - mnew);              \
        rs += (S_[0] + S_[1]) + (S_[2] + S_[3]); }

#define PVF(NT, HH, PB) {                                                        \
        bf16x8 va_ = *(const bf16x8*)(vbase + ((NT) * 16 + lr) * 128 +           \
                                      ((((HH) * 4 + lg) ^ swv) << 4));           \
        o##NT = MFMA16(va_, PB, o##NT); }

#define TILEBODY(QKM) {                                                          \
        QKM(sA, 0, 0) QKM(sB, 0, 1) QKM(sC, 1, 0) QKM(sD, 1, 1)                  \
        float tm = fmaxf(fmaxf(fmaxf(sA[0], sA[1]), fmaxf(sA[2], sA[3])),        \
                         fmaxf(fmaxf(sB[0], sB[1]), fmaxf(sB[2], sB[3])));       \
        tm = fmaxf(tm, fmaxf(fmaxf(fmaxf(sC[0], sC[1]), fmaxf(sC[2], sC[3])),    \
                             fmaxf(fmaxf(sD[0], sD[1]), fmaxf(sD[2], sD[3]))));  \
        tm = fmaxf(tm, __shfl_xor(tm, 16));                                      \
        tm = fmaxf(tm, __shfl_xor(tm, 32));                                      \
        const float mnew = fmaxf(mrun, tm);                                      \
        const float alpha = __expf(mrun - mnew);                                 \
        mrun = mnew;                                                             \
        float rs = 0.f;                                                          \
        EXV(sA) EXV(sB) EXV(sC) EXV(sD)                                          \
        rs += __shfl_xor(rs, 16);                                                \
        rs += __shfl_xor(rs, 32);                                                \
        lsum = lsum * alpha + rs;                                                \
        o0[0] *= alpha; o0[1] *= alpha; o0[2] *= alpha; o0[3] *= alpha;          \
        o1[0] *= alpha; o1[1] *= alpha; o1[2] *= alpha; o1[3] *= alpha;          \
        o2[0] *= alpha; o2[1] *= alpha; o2[2] *= alpha; o2[3] *= alpha;          \
        o3[0] *= alpha; o3[1] *= alpha; o3[2] *= alpha; o3[3] *= alpha;          \
        bf16x8 pb0, pb1;                                                         \
        pb0[0] = (bf16_t)sA[0]; pb0[1] = (bf16_t)sA[1]; pb0[2] = (bf16_t)sA[2]; pb0[3] = (bf16_t)sA[3]; \
        pb0[4] = (bf16_t)sB[0]; pb0[5] = (bf16_t)sB[1]; pb0[6] = (bf16_t)sB[2]; pb0[7] = (bf16_t)sB[3]; \
        pb1[0] = (bf16_t)sC[0]; pb1[1] = (bf16_t)sC[1]; pb1[2] = (bf16_t)sC[2]; pb1[3] = (bf16_t)sC[3]; \
        pb1[4] = (bf16_t)sD[0]; pb1[5] = (bf16_t)sD[1]; pb1[6] = (bf16_t)sD[2]; pb1[7] = (bf16_t)sD[3]; \
        PVF(0, 0, pb0) PVF(1, 0, pb0) PVF(2, 0, pb0) PVF(3, 0, pb0)              \
        PVF(0, 1, pb1) PVF(1, 1, pb1) PVF(2, 1, pb1) PVF(3, 1, pb1)              \
    }

#define SETT(U) kbase = (const char*)kld + (U) * 8192;                           \
                vbase = (const char*)vld + (U) * 8192;                           \
                k0s = (tb + (U)) * 64;

    if (qt >= 4) {
        SETT(0) TILEBODY(QKF_U)
        SETT(1) TILEBODY(QKF_N)
        SETT(2) TILEBODY(QKF_N)
        SETT(3) TILEBODY(QKF_N)
        SETT(4) TILEBODY(QKF_L)
    } else {
#pragma unroll
        for (int u = 0; u < 5; ++u) {
            SETT(u) TILEBODY(QKF_F)
        }
    }
#undef SETT
#undef TILEBODY
#undef QKF_F
#undef QKF_U
#undef QKF_L
#undef QKF_N
#undef QKCORE
#undef EXV
#undef PVF

    const float rinv = 1.0f / lsum;
    bf16_t* aor = Ao + ((long)(b * 2048) + q) * 1024 + h * 64;
#define EPI(NT, OA_) {                                                           \
        bf16x4 ov_;                                                             \
        ov_[0] = (bf16_t)(OA_[0] * rinv); ov_[1] = (bf16_t)(OA_[1] * rinv);      \
        ov_[2] = (bf16_t)(OA_[2] * rinv); ov_[3] = (bf16_t)(OA_[3] * rinv);      \
        *(bf16x4*)(aor + (NT) * 16 + lg * 4) = ov_; }
    EPI(0, o0) EPI(1, o1) EPI(2, o2) EPI(3, o3)
#undef EPI
}

// ---------------------------------------------------------------------------
extern "C" void kernel_launch(void* const* d_in, const int* in_sizes, int n_in,
                              void* d_out, int out_size, void* d_ws, size_t ws_size,
                              hipStream_t stream) {
    (void)in_sizes; (void)n_in; (void)out_size; (void)ws_size;
    const float* x    = (const float*)d_in[0];
    const float* fcos = (const float*)d_in[1];
    const float* fsin = (const float*)d_in[2];
    const float* wq   = (const float*)d_in[3];
    const float* wk   = (const float*)d_in[4];
    const float* wv   = (const float*)d_in[5];
    const float* wo   = (const float*)d_in[6];
    float* out = (float*)d_out;

    char* ws = (char*)d_ws;
    // layout (bytes): xbf 16MB @0 | wqkv 6MB @16M | wobf 2MB @22M |
    //                 qbuf 16MB @40M | kbuf 16MB @72M | vtb 16MB @88M.
    //                 aob reuses xbf (dead after gemm192_qkv).
    bf16_t* xbf   = (bf16_t*)(ws);
    bf16_t* wqkv  = (bf16_t*)(ws + 16777216);
    bf16_t* wobf  = (bf16_t*)(ws + 23068672);
    bf16_t* qbuf  = (bf16_t*)(ws + 41943040);
    bf16_t* kbuf  = (bf16_t*)(ws + 75497472);
    bf16_t* vtb   = (bf16_t*)(ws + 92274688);
    bf16_t* aob   = xbf;   // xbf dead after gemm192_qkv

    cvt_all<<<6144, 256, 0, stream>>>(x, wq, wk, wv, wo, xbf, wqkv, wobf);

    // QKV + fused RoPE/layout/V-transpose: (16,32) = 512 blocks = 2 rounds
    gemm192_qkv<<<dim3(16, 32), 512, 0, stream>>>(xbf, wqkv, fcos, fsin,
                                                  qbuf, kbuf, vtb,
                                                  8192, 3072, 1024);
    attn_win4<<<2048, 256, 0, stream>>>(qbuf, kbuf, vtb, aob);
    // O-proj: grid (8, 32) = 256 blocks = 1 exact round
    gemm256<float><<<dim3(8, 32), 512, 0, stream>>>(aob, wobf, out, 8192, 1024, 1024);
}

// Round 14
// 120.574 us; speedup vs baseline: 1.0589x; 1.0317x over previous
//
#include <hip/hip_runtime.h>
#include <hip/hip_bf16.h>

// ---------------------------------------------------------------------------
// Sliding-window attention (B=4,S=2048,D=1024,H=16,HD=64,W=256) on gfx950.
// Pipeline: cvt(all) -> GEMM(QKV, 256x192 8-phase, FUSED epilogue: LDS
//           transpose; in-lane RoPE (+0.125 prescale on Q); Q/K stored in
//           COL-BLOCK layout [ch/16][8192 tok][16ch] (fully dense 1KB/wave
//           store instructions); V -> VT[bh][64][2048]) ->
//           flash window attn (2-deep pipelined K/V staging, 4 blocks/CU) ->
//           GEMM(O-proj, 256x128 3-buffer).
// ---------------------------------------------------------------------------

typedef __bf16 bf16_t;
typedef __attribute__((ext_vector_type(8))) __bf16 bf16x8;
typedef __attribute__((ext_vector_type(4))) __bf16 bf16x4;
typedef __attribute__((ext_vector_type(4))) float f32x4;

#define MFMA16(a, b, c) __builtin_amdgcn_mfma_f32_16x16x32_bf16((a), (b), (c), 0, 0, 0)

// async global->LDS, 16 bytes per lane. LDS dest is wave-uniform base + lane*16.
__device__ __forceinline__ void async16(const void* g, void* l) {
    __builtin_amdgcn_global_load_lds(
        (const __attribute__((address_space(1))) unsigned int*)g,
        (__attribute__((address_space(3))) unsigned int*)l, 16, 0, 0);
}

#define BAR() do { asm volatile("" ::: "memory"); __builtin_amdgcn_s_barrier(); \
                   asm volatile("" ::: "memory"); } while (0)
#define VMC(N) asm volatile("s_waitcnt vmcnt(" #N ")" ::: "memory")
#define LGKM0() asm volatile("s_waitcnt lgkmcnt(0)" ::: "memory")

// col-block stride for Q/K: [cb][8192 tokens][16 ch]
#define CBS 131072L   // 8192 * 16 elements

// ---------------------------------------------------------------------------
// Fused f32 -> bf16 convert for all 5 tensors, 8 elems/thread.
// ---------------------------------------------------------------------------
__global__ __launch_bounds__(256) void cvt_all(const float* __restrict__ x,
                                               const float* __restrict__ wq,
                                               const float* __restrict__ wk,
                                               const float* __restrict__ wv,
                                               const float* __restrict__ wo,
                                               bf16_t* __restrict__ xbf,
                                               bf16_t* __restrict__ wqkv,
                                               bf16_t* __restrict__ wobf) {
    const int blk = blockIdx.x;
    const float* s;
    bf16_t* d;
    int base;
    if (blk < 4096)      { s = x;  d = xbf;            base = blk; }
    else if (blk < 4608) { s = wq; d = wqkv;           base = blk - 4096; }
    else if (blk < 5120) { s = wk; d = wqkv + 1048576; base = blk - 4608; }
    else if (blk < 5632) { s = wv; d = wqkv + 2097152; base = blk - 5120; }
    else                 { s = wo; d = wobf;           base = blk - 5632; }
    const int i = (base * 256 + threadIdx.x) * 8;
    float4 a = *(const float4*)(s + i);
    float4 b = *(const float4*)(s + i + 4);
    bf16x8 o;
    o[0] = (bf16_t)a.x; o[1] = (bf16_t)a.y; o[2] = (bf16_t)a.z; o[3] = (bf16_t)a.w;
    o[4] = (bf16_t)b.x; o[5] = (bf16_t)b.y; o[6] = (bf16_t)b.z; o[7] = (bf16_t)b.w;
    *(bf16x8*)(d + i) = o;
}

// ---------------------------------------------------------------------------
// 256x192 8-phase QKV GEMM with FUSED epilogue (R14).
// Main loop identical to R4/R6 (counted vmcnt, st_16x32 swizzle, 8 waves).
// Epilogue: per-fragment LDS transpose (scr[tok][ch], stride 20); then
//   q/k: in-lane RoPE (+0.125 prescale on q); COL-BLOCK store: lane (tl,cg)
//        writes token (tl+qq*32)'s 16B half-record at (cb*8192+t)*16+cg*8 --
//        the wave's 64 stores cover 1024 contiguous bytes (no partial lines).
//   v:   within-8 key permutation readback -> VT[bh][64][2048].
// ---------------------------------------------------------------------------
__global__ __launch_bounds__(512, 1) __attribute__((amdgpu_waves_per_eu(2)))
void gemm192_qkv(const bf16_t* __restrict__ A, const bf16_t* __restrict__ Bw,
                 const float* __restrict__ fcos, const float* __restrict__ fsin,
                 bf16_t* __restrict__ Qo, bf16_t* __restrict__ Ko,
                 bf16_t* __restrict__ VT, int M, int N, int K) {
    __shared__ __attribute__((aligned(16))) bf16_t As[32768];   // 2 x 4u x 8KiB
    __shared__ __attribute__((aligned(16))) bf16_t Bs[24576];   // 2 x 3u x 8KiB
    const int tid = threadIdx.x;
    const int l = tid & 63, w = tid >> 6;
    const int lr = l & 15, lg = l >> 4;
    const int wr = w >> 2, wc = w & 3;          // 2M x 4N

    const int nwg = gridDim.x * gridDim.y;
    const int flat = blockIdx.y * gridDim.x + blockIdx.x;
    const int swz = (flat & 7) * (nwg >> 3) + (flat >> 3);
    const int bx = swz % gridDim.x, by = swz / gridDim.x;
    const long m0 = (long)by * 256, n0 = (long)bx * 192;
    const int NT = K >> 6;
    const int NI = NT >> 1;

    const int p  = w * 1024 + l * 16;
    const int pp = p ^ (((p >> 9) & 1) << 5);
    const int st = pp >> 10;
    const int rSt = (st >> 1) * 16 + ((pp >> 6) & 15);
    const int cSt = (st & 1) * 32 + ((pp >> 4) & 3) * 8;
    const bf16_t* aS = A  + (m0 + rSt) * K + cSt;
    const bf16_t* bS = Bw + (n0 + rSt) * K + cSt;
    const long uK = 64L * K;

    auto stageA = [&](int b, int u, int t) {
        async16(aS + (long)u * uK + (long)t * 64,
                (char*)As + b * 32768 + u * 8192 + w * 1024);
    };
    auto stageB = [&](int b, int u, int t) {
        async16(bS + (long)u * uK + (long)t * 64,
                (char*)Bs + b * 24576 + u * 8192 + w * 1024);
    };

    f32x4 acc[8][3] = {};
    bf16x8 afX[4], afY[4], bfX[3], bfY[3];
    const int swd = (lr & 8) << 2;

    auto loadAF = [&](int b, int mh, int ks, bf16x8 (&dst)[4]) {
#pragma unroll
        for (int mi = 0; mi < 4; ++mi) {
            const int off = (wr * 2 + mh) * 8192 + (mi * 2 + ks) * 1024 +
                            lr * 64 + lg * 16;
            dst[mi] = *(const bf16x8*)((const char*)As + b * 32768 + (off ^ swd));
        }
    };
    auto loadBF = [&](int b, int ks, bf16x8 (&dst)[3]) {
#pragma unroll
        for (int nj = 0; nj < 3; ++nj) {
            const int rg = wc * 48 + nj * 16 + lr;
            const int off = (rg >> 6) * 8192 + (((rg >> 4) & 3) * 2 + ks) * 1024 +
                            lr * 64 + lg * 16;
            dst[nj] = *(const bf16x8*)((const char*)Bs + b * 24576 + (off ^ swd));
        }
    };

#define QMM(MH, AF, BF) do {                                                   \
    __builtin_amdgcn_s_setprio(1);                                             \
    _Pragma("unroll")                                                          \
    for (int mi = 0; mi < 4; ++mi)                                             \
        _Pragma("unroll")                                                      \
        for (int nj = 0; nj < 3; ++nj)                                         \
            acc[(MH)*4+mi][nj] = MFMA16((AF)[mi], (BF)[nj], acc[(MH)*4+mi][nj]); \
    __builtin_amdgcn_s_setprio(0);                                             \
} while (0)

    // ---- prologue ----
    stageA(0, 0, 0); stageA(0, 1, 0); stageA(0, 2, 0); stageA(0, 3, 0);
    stageB(0, 0, 0); stageB(0, 1, 0); stageB(0, 2, 0);
    stageB(1, 0, 1); stageB(1, 1, 1); stageB(1, 2, 1);
    VMC(3);
    BAR();

#pragma unroll 1
    for (int it = 0; it < NI - 1; ++it) {
        const int T = 2 * it;
        loadAF(0, 0, 0, afX); loadBF(0, 0, bfX);
        stageA(1, 0, T + 1); stageA(1, 1, T + 1);
        BAR(); QMM(0, afX, bfX); BAR();
        loadAF(0, 1, 0, afY);
        stageA(1, 2, T + 1); stageA(1, 3, T + 1);
        BAR(); QMM(1, afY, bfX); BAR();
        loadAF(0, 0, 1, afX); loadBF(0, 1, bfY);
        BAR(); QMM(0, afX, bfY); BAR();
        loadAF(0, 1, 1, afY);
        stageB(0, 0, T + 2);
        BAR(); QMM(1, afY, bfY); VMC(1); BAR();
        loadAF(1, 0, 0, afX); loadBF(1, 0, bfX);
        stageB(0, 1, T + 2); stageB(0, 2, T + 2);
        BAR(); QMM(0, afX, bfX); BAR();
        loadAF(1, 1, 0, afY);
        stageA(0, 0, T + 2); stageA(0, 1, T + 2);
        BAR(); QMM(1, afY, bfX); BAR();
        loadAF(1, 0, 1, afX); loadBF(1, 1, bfY);
        stageA(0, 2, T + 2); stageA(0, 3, T + 2);
        BAR(); QMM(0, afX, bfY); BAR();
        loadAF(1, 1, 1, afY);
        stageB(1, 0, T + 3); stageB(1, 1, T + 3); stageB(1, 2, T + 3);
        BAR(); QMM(1, afY, bfY); VMC(3); BAR();
    }

    // ---- final iteration (tiles NT-2 buf0, NT-1 buf1) ----
    {
        loadAF(0, 0, 0, afX); loadBF(0, 0, bfX);
        stageA(1, 0, NT - 1); stageA(1, 1, NT - 1);
        BAR(); QMM(0, afX, bfX); BAR();
        loadAF(0, 1, 0, afY);
        stageA(1, 2, NT - 1); stageA(1, 3, NT - 1);
        BAR(); QMM(1, afY, bfX); BAR();
        loadAF(0, 0, 1, afX); loadBF(0, 1, bfY);
        BAR(); QMM(0, afX, bfY); BAR();
        loadAF(0, 1, 1, afY);
        BAR(); QMM(1, afY, bfY);
        VMC(0); BAR();                 // <- after this, buf0 of As/Bs is free
        loadAF(1, 0, 0, afX); loadBF(1, 0, bfX);
        QMM(0, afX, bfX);
        loadAF(1, 1, 0, afY);
        QMM(1, afY, bfX);
        loadAF(1, 0, 1, afX); loadBF(1, 1, bfY);
        QMM(0, afX, bfY);
        loadAF(1, 1, 1, afY);
        QMM(1, afY, bfY);
    }
#undef QMM

    // ---- FUSED epilogue ----
    // per-wave private scratch in buf0 (free): 128 tok x 20 bf16 = 5120 B.
    bf16_t* scr = (w < 6) ? (bf16_t*)((char*)As + w * 5120)
                          : (bf16_t*)((char*)Bs + (w - 6) * 5120);
    asm volatile("" ::: "memory");

    const int tl = l & 31, cg = l >> 5;          // readback lane mapping
    const int chb = cg * 8;                      // channel group base 0/8

#pragma unroll
    for (int nj = 0; nj < 3; ++nj) {
        const int cbase = (int)n0 + wc * 48 + nj * 16;   // multiple of 16
        const int cls = cbase >> 10;                     // 0=q,1=k,2=v (uniform)

        // transpose this fragment: scr[token][channel] (bf16, stride 20)
#pragma unroll
        for (int ai = 0; ai < 8; ++ai)
#pragma unroll
            for (int j = 0; j < 4; ++j)
                scr[(ai * 16 + lg * 4 + j) * 20 + lr] = (bf16_t)acc[ai][nj][j];
        LGKM0();
        asm volatile("" ::: "memory");

        if (cls == 2) {
            // ---- V: within-8 key perm readback -> VT, 64B-line friendly ----
            const int ch = l >> 2;                       // channel 0..15
            const int sub = l & 3;                       // 16B chunk within 64B
            const int d16 = cbase - 2048 + ch;
            const int hh = d16 >> 6, dd = d16 & 63;
            const long T0 = m0 + wr * 128;
            const int bb = (int)(T0 >> 11);
            const int s0 = (int)(T0 & 2047);
            bf16_t* vrow = VT + ((long)((bb * 16 + hh) * 64 + dd) * 2048) + s0;
#pragma unroll
            for (int qq = 0; qq < 4; ++qq) {
                const int tb8 = qq * 32 + sub * 8;       // token base of chunk
                bf16x8 o;
#pragma unroll
                for (int j = 0; j < 8; ++j) {
                    const int f = ((j & 3) << 1) | (j >> 2);  // pos j holds key f
                    o[j] = scr[(tb8 + f) * 20 + ch];
                }
                *(bf16x8*)(vrow + tb8) = o;
            }
        } else {
            // ---- Q/K: in-lane RoPE; COL-BLOCK store (dense 1KB/wave) ----
            const int cq = cbase & 1023;
            const float sc = (cls == 0) ? 0.125f : 1.f;
            bf16_t* qk = ((cls == 0) ? Qo : Ko) + (long)(cq >> 4) * CBS + chb;
            const int p2b = ((cbase & 63) >> 1) + cg * 4;  // 4-aligned
#pragma unroll
            for (int qq = 0; qq < 4; ++qq) {
                const int t = tl + qq * 32;              // token 0..127
                bf16x4 vlo = *(const bf16x4*)&scr[t * 20 + chb];
                bf16x4 vhi = *(const bf16x4*)&scr[t * 20 + chb + 4];
                const long gt = m0 + wr * 128 + t;
                const int s0 = (int)(gt & 2047);
                const float4 cc = *(const float4*)(fcos + s0 * 32 + p2b);
                const float4 sn = *(const float4*)(fsin + s0 * 32 + p2b);
                bf16x8 o;
                float e0, e1;
                e0 = (float)vlo[0]; e1 = (float)vlo[1];
                o[0] = (bf16_t)((e0 * cc.x - e1 * sn.x) * sc);
                o[1] = (bf16_t)((e0 * sn.x + e1 * cc.x) * sc);
                e0 = (float)vlo[2]; e1 = (float)vlo[3];
                o[2] = (bf16_t)((e0 * cc.y - e1 * sn.y) * sc);
                o[3] = (bf16_t)((e0 * sn.y + e1 * cc.y) * sc);
                e0 = (float)vhi[0]; e1 = (float)vhi[1];
                o[4] = (bf16_t)((e0 * cc.z - e1 * sn.z) * sc);
                o[5] = (bf16_t)((e0 * sn.z + e1 * cc.z) * sc);
                e0 = (float)vhi[2]; e1 = (float)vhi[3];
                o[6] = (bf16_t)((e0 * cc.w - e1 * sn.w) * sc);
                o[7] = (bf16_t)((e0 * sn.w + e1 * cc.w) * sc);
                *(bf16x8*)(qk + gt * 16) = o;
            }
        }
        LGKM0();                       // all reads of scr done before reuse
        asm volatile("" ::: "memory");
    }
}

// ---------------------------------------------------------------------------
// 256x128 GEMM (O-proj: N=1024 -> 256 blocks = 1 exact round).
// Triple-buffered deep prefetch, counted vmcnt (R3/R4 version).
// ---------------------------------------------------------------------------
template <typename OUT>
__global__ __launch_bounds__(512, 2) void gemm256(const bf16_t* __restrict__ A,
                                                  const bf16_t* __restrict__ Bw,
                                                  OUT* __restrict__ C,
                                                  int M, int N, int K) {
    __shared__ __attribute__((aligned(16))) bf16_t As[49152];   // 3 x 2 x 128x64
    __shared__ __attribute__((aligned(16))) bf16_t Bs[24576];   // 3 x 128x64
    const int tid = threadIdx.x;
    const int l = tid & 63, w = tid >> 6;
    const int lr = l & 15, lg = l >> 4;
    const int wr = w >> 1, wc = w & 1;

    const int nwg = gridDim.x * gridDim.y;
    const int flat = blockIdx.y * gridDim.x + blockIdx.x;
    const int swz = (flat & 7) * (nwg >> 3) + (flat >> 3);
    const int bx = swz % gridDim.x, by = swz / gridDim.x;
    const long m0 = (long)by * 256, n0 = (long)bx * 128;
    const int NT = K >> 6;

    int rS[2], cS[2];
#pragma unroll
    for (int i = 0; i < 2; ++i) {
        const int p  = i * 8192 + w * 1024 + l * 16;
        const int pp = p ^ (((p >> 9) & 1) << 5);
        const int st = pp >> 10;
        rS[i] = (st >> 1) * 16 + ((pp >> 6) & 15);
        cS[i] = (st & 1) * 32 + ((pp >> 4) & 3) * 8;
    }
    const bf16_t* aSrc0 = A  + (m0 + rS[0]) * K + cS[0];
    const bf16_t* aSrc1 = A  + (m0 + rS[1]) * K + cS[1];
    const bf16_t* bSrc0 = Bw + (n0 + rS[0]) * K + cS[0];
    const bf16_t* bSrc1 = Bw + (n0 + rS[1]) * K + cS[1];
    const long hK = 128L * K;

    auto stageA = [&](int b, int h, int t) {
        char* d = (char*)As + b * 32768 + h * 16384 + w * 1024;
        const long o = (long)h * hK + (long)t * 64;
        async16(aSrc0 + o, d);
        async16(aSrc1 + o, d + 8192);
    };
    auto stageB = [&](int b, int t) {
        char* d = (char*)Bs + b * 16384 + w * 1024;
        const long o = (long)t * 64;
        async16(bSrc0 + o, d);
        async16(bSrc1 + o, d + 8192);
    };

    f32x4 acc[4][4] = {};
    bf16x8 af[4][2], blo[2][2], bhi[2][2];
    const int swd = (lr & 8) << 2;

    auto loadA = [&](int b) {
#pragma unroll
        for (int mi = 0; mi < 4; ++mi)
#pragma unroll
            for (int ks = 0; ks < 2; ++ks) {
                const int ra = (wr & 1) * 64 + mi * 16 + lr;
                const int off = ((ra >> 4) * 2 + ks) * 1024 + (ra & 15) * 64 + lg * 16;
                af[mi][ks] = *(const bf16x8*)((const char*)As + b * 32768 +
                                              (wr >> 1) * 16384 + (off ^ swd));
            }
    };
    auto loadB = [&](int b, int nh, bf16x8 (&dst)[2][2]) {
#pragma unroll
        for (int nj = 0; nj < 2; ++nj)
#pragma unroll
            for (int ks = 0; ks < 2; ++ks) {
                const int rb = wc * 64 + (nh * 2 + nj) * 16 + lr;
                const int off = ((rb >> 4) * 2 + ks) * 1024 + (rb & 15) * 64 + lg * 16;
                dst[nj][ks] = *(const bf16x8*)((const char*)Bs + b * 16384 +
                                               (off ^ swd));
            }
    };

#define QMM(NH, BF) do {                                                       \
    __builtin_amdgcn_s_setprio(1);                                             \
    _Pragma("unroll")                                                          \
    for (int mi = 0; mi < 4; ++mi) {                                           \
        acc[mi][(NH)*2]   = MFMA16(af[mi][0], (BF)[0][0], acc[mi][(NH)*2]);    \
        acc[mi][(NH)*2]   = MFMA16(af[mi][1], (BF)[0][1], acc[mi][(NH)*2]);    \
        acc[mi][(NH)*2+1] = MFMA16(af[mi][0], (BF)[1][0], acc[mi][(NH)*2+1]);  \
        acc[mi][(NH)*2+1] = MFMA16(af[mi][1], (BF)[1][1], acc[mi][(NH)*2+1]);  \
    }                                                                          \
    __builtin_amdgcn_s_setprio(0);                                             \
} while (0)

    stageA(0, 0, 0); stageA(0, 1, 0); stageB(0, 0);
    stageA(1, 0, 1); stageA(1, 1, 1); stageB(1, 1);
    VMC(6);
    BAR();

    int bc = 0;
#pragma unroll 1
    for (int t = 0; t < NT - 2; ++t) {
        const int bn = (bc + 2 >= 3) ? bc - 1 : bc + 2;
        loadA(bc); loadB(bc, 0, blo); stageA(bn, 0, t + 2); stageA(bn, 1, t + 2);
        BAR(); QMM(0, blo); BAR();
        loadB(bc, 1, bhi); stageB(bn, t + 2);
        BAR(); QMM(1, bhi);
        if (t < NT - 3) { VMC(6); } else { VMC(0); }
        BAR();
        bc = (bc + 1 >= 3) ? 0 : bc + 1;
    }
    {
        loadA(bc); loadB(bc, 0, blo);
        QMM(0, blo);
        loadB(bc, 1, bhi);
        QMM(1, bhi);
        const int b2 = (bc + 1 >= 3) ? 0 : bc + 1;
        loadA(b2); loadB(b2, 0, blo);
        QMM(0, blo);
        loadB(b2, 1, bhi);
        QMM(1, bhi);
    }
#undef QMM

#pragma unroll
    for (int mi = 0; mi < 4; ++mi)
#pragma unroll
        for (int ni = 0; ni < 4; ++ni)
#pragma unroll
            for (int j = 0; j < 4; ++j) {
                long r = m0 + wr * 64 + mi * 16 + lg * 4 + j;
                long c = n0 + wc * 64 + ni * 16 + lr;
                C[r * N + c] = (OUT)acc[mi][ni][j];
            }
}

// ---------------------------------------------------------------------------
// Sliding-window attention v9: 2-deep pipelined K/V staging (32 KiB LDS ->
// 4 blocks/CU); per tile: stage(u+1) -> compute(u) -> VMC(0)+BAR (stage has
// a full tile's compute to land; trailing barrier fences buffer reuse).
// Q/K inputs in COL-BLOCK layout [ch/16][8192][16].  Online softmax per
// 64-key tile, swapped QK^T, prescaled Q; mask specialization for qt>=4.
// ---------------------------------------------------------------------------
__global__ __launch_bounds__(256, 4) void attn_win4(const bf16_t* __restrict__ Q,
                                                    const bf16_t* __restrict__ Kb,
                                                    const bf16_t* __restrict__ VT,
                                                    bf16_t* __restrict__ Ao) {
    __shared__ __attribute__((aligned(16))) bf16_t kld[2 * 4096];
    __shared__ __attribute__((aligned(16))) bf16_t vld[2 * 4096];
    const int raw = blockIdx.x;
    const int mswz = ((raw & 7) << 8) | (raw >> 3);
    const int qt = mswz & 31, bh = mswz >> 5;
    const int h = bh & 15, b = bh >> 4;
    const int l = threadIdx.x & 63, w = threadIdx.x >> 6;
    const int lr = l & 15, lg = l >> 4;
    const int q0 = qt * 64 + w * 16;
    const int q = q0 + lr;
    const int tb = qt - 4;

    // col-block Q/K: base includes head (4h blocks) and batch token offset
    const bf16_t* Qh = Q  + (long)(4 * h) * CBS + (long)(b * 2048) * 16;
    const bf16_t* Kh = Kb + (long)(4 * h) * CBS + (long)(b * 2048) * 16;
    const bf16_t* Vp = VT + (long)bh * 64 * 2048;

    // stage tile u (K + V, 4 async16/thread) into buffer slot bs
    auto stageT = [&](int u, int bs) {
        const int kt = tb + u;
        const int kt64 = (kt < 0 ? 0 : kt) * 64;
#pragma unroll
        for (int part = 0; part < 2; ++part) {
            const int seg = w * 2 + part;              // 1 KB segment 0..7
            const int r = seg * 8 + (l >> 3);          // row within 64-row tile
            const int sc = (l & 7) ^ ((r >> 1) & 7);   // swizzled 16B chunk
            async16(Kh + (sc >> 1) * CBS + (long)(kt64 + r) * 16 + (sc & 1) * 8,
                    (char*)kld + bs * 8192 + seg * 1024);
            async16(Vp + (long)r * 2048 + kt64 + sc * 8,
                    (char*)vld + bs * 8192 + seg * 1024);
        }
    };

    // ---- prologue: stage tile 0; load Q fragments; certify ----
    stageT(0, 0);
    const bf16x8 qb0 = *(const bf16x8*)&Qh[(lg >> 1) * CBS + (long)q * 16 + (lg & 1) * 8];
    const bf16x8 qb1 = *(const bf16x8*)&Qh[(2 + (lg >> 1)) * CBS + (long)q * 16 + (lg & 1) * 8];
    VMC(0);
    BAR();

    float mrun = -1000.f, lsum = 0.f;
    f32x4 o0 = {0.f, 0.f, 0.f, 0.f}, o1 = {0.f, 0.f, 0.f, 0.f};
    f32x4 o2 = {0.f, 0.f, 0.f, 0.f}, o3 = {0.f, 0.f, 0.f, 0.f};
    const int swv = (lr >> 1) & 7;

    const char* kbase;
    const char* vbase;
    int k0s;

#define QKCORE(HH, MM)                                                           \
        const int row_ = (HH) * 32 + 2 * lr + (MM);                              \
        const int sw_ = (row_ >> 1) & 7;                                         \
        bf16x8 k0_ = *(const bf16x8*)(kbase + row_ * 128 + ((lg ^ sw_) << 4));   \
        bf16x8 k1_ = *(const bf16x8*)(kbase + row_ * 128 + (((4 + lg) ^ sw_) << 4)); \
        f32x4 s_ = {0.f, 0.f, 0.f, 0.f};                                         \
        s_ = MFMA16(k0_, qb0, s_);                                               \
        s_ = MFMA16(k1_, qb1, s_);

#define QKF_F(DST, HH, MM)                                                       \
    f32x4 DST; { QKCORE(HH, MM)                                                  \
        const int kb_ = k0s + (HH) * 32 + (MM) + lg * 8;                         \
        DST[0] = ((kb_ >= 0) & ((unsigned)(q - kb_) < 256u))         ? s_[0] : -1e30f; \
        DST[1] = ((kb_ + 2 >= 0) & ((unsigned)(q - kb_ - 2) < 256u)) ? s_[1] : -1e30f; \
        DST[2] = ((kb_ + 4 >= 0) & ((unsigned)(q - kb_ - 4) < 256u)) ? s_[2] : -1e30f; \
        DST[3] = ((kb_ + 6 >= 0) & ((unsigned)(q - kb_ - 6) < 256u)) ? s_[3] : -1e30f; \
    }

#define QKF_U(DST, HH, MM)                                                       \
    f32x4 DST; { QKCORE(HH, MM)                                                  \
        const int d_ = q - (k0s + (HH) * 32 + (MM) + lg * 8);                    \
        DST[0] = (d_ < 256)     ? s_[0] : -1e30f;                                \
        DST[1] = (d_ - 2 < 256) ? s_[1] : -1e30f;                                \
        DST[2] = (d_ - 4 < 256) ? s_[2] : -1e30f;                                \
        DST[3] = (d_ - 6 < 256) ? s_[3] : -1e30f;                                \
    }

#define QKF_L(DST, HH, MM)                                                       \
    f32x4 DST; { QKCORE(HH, MM)                                                  \
        const int d_ = q - (k0s + (HH) * 32 + (MM) + lg * 8);                    \
        DST[0] = (d_ >= 0)     ? s_[0] : -1e30f;                                 \
        DST[1] = (d_ - 2 >= 0) ? s_[1] : -1e30f;                                 \
        DST[2] = (d_ - 4 >= 0) ? s_[2] : -1e30f;                                 \
        DST[3] = (d_ - 6 >= 0) ? s_[3] : -1e30f;                                 \
    }

#define QKF_N(DST, HH, MM)                                                       \
    f32x4 DST; { QKCORE(HH, MM)                                                  \
        DST[0] = s_[0]; DST[1] = s_[1]; DST[2] = s_[2]; DST[3] = s_[3];          \
    }

#define EXV(S_) {                                                                \
        S_[0] = __expf(S_[0] - mnew); S_[1] = __expf(S_[1] - mnew);              \
        S_[2] = __expf(S_[2] - mnew); S_[3] = __expf(S_[3] - mnew);              \
        rs += (S_[0] + S_[1]) + (S_[2] + S_[3]); }

#define PVF(NT, HH, PB) {                                                        \
        bf16x8 va_ = *(const bf16x8*)(vbase + ((NT) * 16 + lr) * 128 +           \
                                      ((((HH) * 4 + lg) ^ swv) << 4));           \
        o##NT = MFMA16(va_, PB, o##NT); }

#define TILEBODY(QKM) {                                                          \
        QKM(sA, 0, 0) QKM(sB, 0, 1) QKM(sC, 1, 0) QKM(sD, 1, 1)                  \
        float tm = fmaxf(fmaxf(fmaxf(sA[0], sA[1]), fmaxf(sA[2], sA[3])),        \
                         fmaxf(fmaxf(sB[0], sB[1]), fmaxf(sB[2], sB[3])));       \
        tm = fmaxf(tm, fmaxf(fmaxf(fmaxf(sC[0], sC[1]), fmaxf(sC[2], sC[3])),    \
                             fmaxf(fmaxf(sD[0], sD[1]), fmaxf(sD[2], sD[3]))));  \
        tm = fmaxf(tm, __shfl_xor(tm, 16));                                      \
        tm = fmaxf(tm, __shfl_xor(tm, 32));                                      \
        const float mnew = fmaxf(mrun, tm);                                      \
        const float alpha = __expf(mrun - mnew);                                 \
        mrun = mnew;                                                             \
        float rs = 0.f;                                                          \
        EXV(sA) EXV(sB) EXV(sC) EXV(sD)                                          \
        rs += __shfl_xor(rs, 16);                                                \
        rs += __shfl_xor(rs, 32);                                                \
        lsum = lsum * alpha + rs;                                                \
        o0[0] *= alpha; o0[1] *= alpha; o0[2] *= alpha; o0[3] *= alpha;          \
        o1[0] *= alpha; o1[1] *= alpha; o1[2] *= alpha; o1[3] *= alpha;          \
        o2[0] *= alpha; o2[1] *= alpha; o2[2] *= alpha; o2[3] *= alpha;          \
        o3[0] *= alpha; o3[1] *= alpha; o3[2] *= alpha; o3[3] *= alpha;          \
        bf16x8 pb0, pb1;                                                         \
        pb0[0] = (bf16_t)sA[0]; pb0[1] = (bf16_t)sA[1]; pb0[2] = (bf16_t)sA[2]; pb0[3] = (bf16_t)sA[3]; \
        pb0[4] = (bf16_t)sB[0]; pb0[5] = (bf16_t)sB[1]; pb0[6] = (bf16_t)sB[2]; pb0[7] = (bf16_t)sB[3]; \
        pb1[0] = (bf16_t)sC[0]; pb1[1] = (bf16_t)sC[1]; pb1[2] = (bf16_t)sC[2]; pb1[3] = (bf16_t)sC[3]; \
        pb1[4] = (bf16_t)sD[0]; pb1[5] = (bf16_t)sD[1]; pb1[6] = (bf16_t)sD[2]; pb1[7] = (bf16_t)sD[3]; \
        PVF(0, 0, pb0) PVF(1, 0, pb0) PVF(2, 0, pb0) PVF(3, 0, pb0)              \
        PVF(0, 1, pb1) PVF(1, 1, pb1) PVF(2, 1, pb1) PVF(3, 1, pb1)              \
    }

// pipelined iteration: stage(u+1) early, compute(u), drain+fence
#define ITER(U, QKM) {                                                           \
        if ((U) < 4) stageT((U) + 1, ((U) + 1) & 1);                             \
        kbase = (const char*)kld + ((U) & 1) * 8192;                             \
        vbase = (const char*)vld + ((U) & 1) * 8192;                             \
        k0s = (tb + (U)) * 64;                                                   \
        TILEBODY(QKM)                                                            \
        if ((U) < 4) { VMC(0); BAR(); }                                          \
    }

    if (qt >= 4) {
        ITER(0, QKF_U)
        ITER(1, QKF_N)
        ITER(2, QKF_N)
        ITER(3, QKF_N)
        ITER(4, QKF_L)
    } else {
        ITER(0, QKF_F)
        ITER(1, QKF_F)
        ITER(2, QKF_F)
        ITER(3, QKF_F)
        ITER(4, QKF_F)
    }
#undef ITER
#undef TILEBODY
#undef QKF_F
#undef QKF_U
#undef QKF_L
#undef QKF_N
#undef QKCORE
#undef EXV
#undef PVF

    const float rinv = 1.0f / lsum;
    bf16_t* aor = Ao + ((long)(b * 2048) + q) * 1024 + h * 64;
#define EPI(NT, OA_) {                                                           \
        bf16x4 ov_;                                                             \
        ov_[0] = (bf16_t)(OA_[0] * rinv); ov_[1] = (bf16_t)(OA_[1] * rinv);      \
        ov_[2] = (bf16_t)(OA_[2] * rinv); ov_[3] = (bf16_t)(OA_[3] * rinv);      \
        *(bf16x4*)(aor + (NT) * 16 + lg * 4) = ov_; }
    EPI(0, o0) EPI(1, o1) EPI(2, o2) EPI(3, o3)
#undef EPI
}

// ---------------------------------------------------------------------------
extern "C" void kernel_launch(void* const* d_in, const int* in_sizes, int n_in,
                              void* d_out, int out_size, void* d_ws, size_t ws_size,
                              hipStream_t stream) {
    (void)in_sizes; (void)n_in; (void)out_size; (void)ws_size;
    const float* x    = (const float*)d_in[0];
    const float* fcos = (const float*)d_in[1];
    const float* fsin = (const float*)d_in[2];
    const float* wq   = (const float*)d_in[3];
    const float* wk   = (const float*)d_in[4];
    const float* wv   = (const float*)d_in[5];
    const float* wo   = (const float*)d_in[6];
    float* out = (float*)d_out;

    char* ws = (char*)d_ws;
    // layout (bytes): xbf 16MB @0 | wqkv 6MB @16M | wobf 2MB @22M |
    //                 qbuf 16MB @40M | kbuf 16MB @72M | vtb 16MB @88M.
    //                 aob reuses xbf (dead after gemm192_qkv).
    bf16_t* xbf   = (bf16_t*)(ws);
    bf16_t* wqkv  = (bf16_t*)(ws + 16777216);
    bf16_t* wobf  = (bf16_t*)(ws + 23068672);
    bf16_t* qbuf  = (bf16_t*)(ws + 41943040);
    bf16_t* kbuf  = (bf16_t*)(ws + 75497472);
    bf16_t* vtb   = (bf16_t*)(ws + 92274688);
    bf16_t* aob   = xbf;   // xbf dead after gemm192_qkv

    cvt_all<<<6144, 256, 0, stream>>>(x, wq, wk, wv, wo, xbf, wqkv, wobf);

    // QKV + fused RoPE/layout/V-transpose: (16,32) = 512 blocks = 2 rounds
    gemm192_qkv<<<dim3(16, 32), 512, 0, stream>>>(xbf, wqkv, fcos, fsin,
                                                  qbuf, kbuf, vtb,
                                                  8192, 3072, 1024);
    attn_win4<<<2048, 256, 0, stream>>>(qbuf, kbuf, vtb, aob);
    // O-proj: grid (8, 32) = 256 blocks = 1 exact round
    gemm256<float><<<dim3(8, 32), 512, 0, stream>>>(aob, wobf, out, 8192, 1024, 1024);
}